// Round 1
// baseline (309.091 us; speedup 1.0000x reference)
//
#include <hip/hip_runtime.h>

typedef unsigned short u16;
typedef __attribute__((ext_vector_type(4))) float f32x4;
typedef __attribute__((ext_vector_type(8))) __bf16 bf16x8;
typedef __attribute__((ext_vector_type(8))) unsigned short u16x8;
typedef __attribute__((ext_vector_type(4))) unsigned short u16x4;

// ---------- scalar bf16 helpers (avoid hip_bf16 header API drift) ----------
__device__ __forceinline__ u16 f2b(float f) {
    unsigned int u = __builtin_bit_cast(unsigned int, f);
    u = (u + 0x7FFFu + ((u >> 16) & 1u)) >> 16;
    return (u16)u;
}
__device__ __forceinline__ float b2f(u16 h) {
    unsigned int u = ((unsigned int)h) << 16;
    return __builtin_bit_cast(float, u);
}

// async global->LDS, 16B per lane; LDS dest must be wave-uniform base (+lane*16 by HW)
__device__ __forceinline__ void gload_lds16(const u16* g, u16* l) {
    __builtin_amdgcn_global_load_lds(
        (const __attribute__((address_space(1))) void*)g,
        (__attribute__((address_space(3))) void*)l,
        16, 0, 0);
}

__device__ __forceinline__ bf16x8 lds_frag(const u16* p) {
    u16x8 t = *(const u16x8*)p;
    return __builtin_bit_cast(bf16x8, t);
}

// ---------------- prep kernels ----------------
__global__ __launch_bounds__(256) void cast_x_kernel(const float* __restrict__ in,
                                                     u16* __restrict__ out) {
    int i = (blockIdx.x * 256 + threadIdx.x) * 4;
    float4 v = *(const float4*)&in[i];
    u16x4 o = { f2b(v.x), f2b(v.y), f2b(v.z), f2b(v.w) };
    *(u16x4*)&out[i] = o;
}

// WqkvT[n][d] = w_sel[h][d][e], n = sel*1024 + h*64 + e ; also bias vec [3072]
__global__ __launch_bounds__(256) void prep_wqkv_kernel(
    const float* __restrict__ wq, const float* __restrict__ wk, const float* __restrict__ wv,
    const float* __restrict__ bq, const float* __restrict__ bk, const float* __restrict__ bv,
    u16* __restrict__ WT, float* __restrict__ BI) {
    int idx = blockIdx.x * 256 + threadIdx.x;     // < 3072*1024
    int n = idx >> 10, d = idx & 1023;
    int sel = n >> 10, hh = (n & 1023) >> 6, e = n & 63;
    const float* w = (sel == 0) ? wq : (sel == 1) ? wk : wv;
    WT[idx] = f2b(w[(hh * 1024 + d) * 64 + e]);
    if (idx < 3072) {
        const float* bb = (idx < 1024) ? bq : (idx < 2048) ? bk : bv;
        BI[idx] = bb[((idx & 1023) >> 6) * 64 + (idx & 63)];
    }
}

// out[c][r] = (bf16) in[r][c]   (in: [R][C] f32)
__global__ __launch_bounds__(256) void transpose_cast(const float* __restrict__ in,
                                                      u16* __restrict__ out, int R, int C) {
    __shared__ float tile[32][33];
    int tx = threadIdx.x & 31, ty = threadIdx.x >> 5;   // 32 x 8
    int r0 = blockIdx.y * 32, c0 = blockIdx.x * 32;
#pragma unroll
    for (int i = 0; i < 32; i += 8)
        tile[ty + i][tx] = in[(long)(r0 + ty + i) * C + c0 + tx];
    __syncthreads();
#pragma unroll
    for (int i = 0; i < 32; i += 8)
        out[(long)(c0 + ty + i) * R + r0 + tx] = f2b(tile[tx][ty + i]);
}

// ---------------- main 128x128 bf16 GEMM (m97 structure) ----------------
// C[M,N] = A[M,K] @ BT[N,K]^T  (+bias[col]).
// MODE 1: f32 out to Cf. MODE 2: relu, bf16 out to Cb. MODE 3: bf16 out to Cb + f32 side
// write of cols>=1024 into KV (Kc then Vc, each 4096x1024).
template <int MODE>
__global__ __launch_bounds__(256) void gemm128(
    const u16* __restrict__ A, const u16* __restrict__ BT, const float* __restrict__ bias,
    u16* __restrict__ Cb, float* __restrict__ Cf, float* __restrict__ KV,
    int M, int N, int K, int lda, int ldb, int ldc) {
    __shared__ __align__(16) u16 As[128 * 32];
    __shared__ __align__(16) u16 Bs[128 * 32];
    const int tid = threadIdx.x;
    const int wid = tid >> 6, lane = tid & 63;
    const int ntile = N >> 7;
    const int bi = blockIdx.x / ntile, bj = blockIdx.x % ntile;
    const int brow = bi * 128, bcol = bj * 128;
    const int wr = wid >> 1, wc = wid & 1;

    f32x4 acc[4][4] = {};
    const u16* Abase = A + (long)brow * lda;
    const u16* Bbase = BT + (long)bcol * ldb;

    for (int k0 = 0; k0 < K; k0 += 32) {
#pragma unroll
        for (int i = 0; i < 2; ++i) {
            int c = i * 256 + tid;               // chunk: row=c>>2, kc=c&3 (8 elems each)
            gload_lds16(Abase + (c >> 2) * lda + k0 + (c & 3) * 8, &As[(i * 256 + wid * 64) * 8]);
            gload_lds16(Bbase + (c >> 2) * ldb + k0 + (c & 3) * 8, &Bs[(i * 256 + wid * 64) * 8]);
        }
        __syncthreads();
        bf16x8 af[4], bfr[4];
#pragma unroll
        for (int m = 0; m < 4; ++m)
            af[m] = lds_frag(&As[(wr * 64 + m * 16 + (lane & 15)) * 32 + (lane >> 4) * 8]);
#pragma unroll
        for (int n = 0; n < 4; ++n)
            bfr[n] = lds_frag(&Bs[(wc * 64 + n * 16 + (lane & 15)) * 32 + (lane >> 4) * 8]);
#pragma unroll
        for (int m = 0; m < 4; ++m)
#pragma unroll
            for (int n = 0; n < 4; ++n)
                acc[m][n] = __builtin_amdgcn_mfma_f32_16x16x32_bf16(af[m], bfr[n], acc[m][n], 0, 0, 0);
        __syncthreads();
    }

#pragma unroll
    for (int m = 0; m < 4; ++m)
#pragma unroll
        for (int n = 0; n < 4; ++n) {
            int col = bcol + wc * 64 + n * 16 + (lane & 15);
            float bv = bias[col];
#pragma unroll
            for (int r = 0; r < 4; ++r) {
                int row = brow + wr * 64 + m * 16 + (lane >> 4) * 4 + r;
                float v = acc[m][n][r] + bv;
                if (MODE == 2) v = v > 0.f ? v : 0.f;
                if (MODE == 1) {
                    Cf[(long)row * ldc + col] = v;
                } else {
                    Cb[(long)row * ldc + col] = f2b(v);
                    if (MODE == 3 && col >= 1024) {
                        int c = col - 1024;
                        KV[(long)(c >> 10) * 4194304 + (long)row * 1024 + (c & 1023)] = v;
                    }
                }
            }
        }
}

// ---------------- K^T V partial sums (t-chunked, f32 atomics) ----------------
// grid (8 tchunks, 32 bh). KTVF[bh][i(e_k)][j(e_v)] += sum_t K[t,i] V[t,j]
__global__ __launch_bounds__(256) void ktv_partial(const u16* __restrict__ QKVB,
                                                   float* __restrict__ KTVF) {
    __shared__ __align__(16) u16 Ks[64 * 64];
    __shared__ __align__(16) u16 Vs[64 * 64];
    int tid = threadIdx.x;
    int tc = blockIdx.x, bh = blockIdx.y;
    int b = bh >> 4, h = bh & 15;
    int j = tid & 63, i0 = (tid >> 6) * 16;
    float acc[16] = {};
    for (int st = 0; st < 4; ++st) {
        int t0 = tc * 256 + st * 64;
        __syncthreads();
#pragma unroll
        for (int i = 0; i < 2; ++i) {
            int c = i * 256 + tid;               // row=c>>3, ch=c&7
            long base = (long)(b * 2048 + t0 + (c >> 3)) * 3072 + h * 64 + (c & 7) * 8;
            *(u16x8*)&Ks[c * 8] = *(const u16x8*)&QKVB[base + 1024];
            *(u16x8*)&Vs[c * 8] = *(const u16x8*)&QKVB[base + 2048];
        }
        __syncthreads();
        for (int tt = 0; tt < 64; ++tt) {
            float vj = b2f(Vs[tt * 64 + j]);
            u16x8 k0 = *(const u16x8*)&Ks[tt * 64 + i0];
            u16x8 k1 = *(const u16x8*)&Ks[tt * 64 + i0 + 8];
#pragma unroll
            for (int r = 0; r < 8; ++r) acc[r] += b2f(k0[r]) * vj;
#pragma unroll
            for (int r = 0; r < 8; ++r) acc[r + 8] += b2f(k1[r]) * vj;
        }
    }
#pragma unroll
    for (int r = 0; r < 16; ++r)
        atomicAdd(&KTVF[bh * 4096 + (i0 + r) * 64 + j], acc[r]);
}

// KTVT[bh][n][k] = KTVF[bh][k][n] * 0.125 (fold 1/sqrt(64))
__global__ __launch_bounds__(256) void cast_ktv(const float* __restrict__ KTVF,
                                                u16* __restrict__ KTVT) {
    int idx = blockIdx.x * 256 + threadIdx.x;   // < 32*4096
    int bh = idx >> 12, r = idx & 4095;
    int n = r >> 6, k = r & 63;
    KTVT[idx] = f2b(KTVF[bh * 4096 + k * 64 + n] * 0.125f);
}

// ---------------- batched attn GEMM: cat[t, h*64+e'] = Q[t,:] @ KTVT[e',:] ----------------
// grid (32 row-tiles, 32 bh)
__global__ __launch_bounds__(256) void attn_gemm(const u16* __restrict__ QKVB,
                                                 const u16* __restrict__ KTVT,
                                                 u16* __restrict__ cat) {
    __shared__ __align__(16) u16 Qs[64 * 64];
    __shared__ __align__(16) u16 Bs[64 * 64];
    int tid = threadIdx.x, wid = tid >> 6, lane = tid & 63;
    int rt = blockIdx.x, bh = blockIdx.y;
    int b = bh >> 4, h = bh & 15;
    long qbase = (long)(b * 2048 + rt * 64) * 3072 + h * 64;
#pragma unroll
    for (int i = 0; i < 2; ++i) {
        int c = i * 256 + tid;                   // row=c>>3, ch=c&7
        gload_lds16(QKVB + qbase + (c >> 3) * 3072 + (c & 7) * 8, &Qs[(i * 256 + wid * 64) * 8]);
        gload_lds16(KTVT + bh * 4096 + c * 8, &Bs[(i * 256 + wid * 64) * 8]);
    }
    __syncthreads();
    f32x4 acc[4] = {};
#pragma unroll
    for (int kk = 0; kk < 2; ++kk) {
        bf16x8 a = lds_frag(&Qs[(wid * 16 + (lane & 15)) * 64 + kk * 32 + (lane >> 4) * 8]);
#pragma unroll
        for (int n = 0; n < 4; ++n) {
            bf16x8 bb = lds_frag(&Bs[(n * 16 + (lane & 15)) * 64 + kk * 32 + (lane >> 4) * 8]);
            acc[n] = __builtin_amdgcn_mfma_f32_16x16x32_bf16(a, bb, acc[n], 0, 0, 0);
        }
    }
#pragma unroll
    for (int n = 0; n < 4; ++n)
#pragma unroll
        for (int r = 0; r < 4; ++r) {
            int row = rt * 64 + wid * 16 + (lane >> 4) * 4 + r;   // t within batch
            int col = h * 64 + n * 16 + (lane & 15);
            cat[(long)(b * 2048 + row) * 1024 + col] = f2b(acc[n][r]);
        }
}

// ---------------- layernorm kernels ----------------
__device__ __forceinline__ void block_reduce2(float& a, float& b) {
    __syncthreads();             // safe LDS reuse across calls
#pragma unroll
    for (int off = 32; off; off >>= 1) {
        a += __shfl_down(a, off);
        b += __shfl_down(b, off);
    }
    __shared__ float sa[4], sb[4];
    int wid = threadIdx.x >> 6, lane = threadIdx.x & 63;
    if (lane == 0) { sa[wid] = a; sb[wid] = b; }
    __syncthreads();
    a = sa[0] + sa[1] + sa[2] + sa[3];
    b = sb[0] + sb[1] + sb[2] + sb[3];
}

// out1 = LN(x + outp) ; write f32 + bf16
__global__ __launch_bounds__(256) void ln1_kernel(
    const float* __restrict__ x, const float* __restrict__ outp,
    const float* __restrict__ g, const float* __restrict__ bt,
    float* __restrict__ out1f, u16* __restrict__ out1b) {
    int row = blockIdx.x, tid = threadIdx.x;
    long base = (long)row * 1024 + tid * 4;
    float4 xv = *(const float4*)&x[base];
    float4 ov = *(const float4*)&outp[base];
    float s[4] = { xv.x + ov.x, xv.y + ov.y, xv.z + ov.z, xv.w + ov.w };
    float sum = s[0] + s[1] + s[2] + s[3];
    float sq = s[0] * s[0] + s[1] * s[1] + s[2] * s[2] + s[3] * s[3];
    block_reduce2(sum, sq);
    float mu = sum * (1.f / 1024.f);
    float var = sq * (1.f / 1024.f) - mu * mu;
    float rs = rsqrtf(var + 1e-5f);
    float4 of;
    u16x4 ob;
    float o0 = (s[0] - mu) * rs * g[tid * 4 + 0] + bt[tid * 4 + 0];
    float o1 = (s[1] - mu) * rs * g[tid * 4 + 1] + bt[tid * 4 + 1];
    float o2 = (s[2] - mu) * rs * g[tid * 4 + 2] + bt[tid * 4 + 2];
    float o3 = (s[3] - mu) * rs * g[tid * 4 + 3] + bt[tid * 4 + 3];
    of.x = o0; of.y = o1; of.z = o2; of.w = o3;
    ob = (u16x4){ f2b(o0), f2b(o1), f2b(o2), f2b(o3) };
    *(float4*)&out1f[base] = of;
    *(u16x4*)&out1b[base] = ob;
}

// ffo = LN(out1+ff); out2 = LN(out1+ffo) -> d_out
__global__ __launch_bounds__(256) void lnf_kernel(
    const float* __restrict__ out1f, const float* __restrict__ ff,
    const float* __restrict__ lnfg, const float* __restrict__ lnfb,
    const float* __restrict__ ln2g, const float* __restrict__ ln2b,
    float* __restrict__ out2) {
    int row = blockIdx.x, tid = threadIdx.x;
    long base = (long)row * 1024 + tid * 4;
    float4 o1 = *(const float4*)&out1f[base];
    float4 fv = *(const float4*)&ff[base];
    float s1[4] = { o1.x + fv.x, o1.y + fv.y, o1.z + fv.z, o1.w + fv.w };
    float sum = s1[0] + s1[1] + s1[2] + s1[3];
    float sq = s1[0] * s1[0] + s1[1] * s1[1] + s1[2] * s1[2] + s1[3] * s1[3];
    block_reduce2(sum, sq);
    float mu = sum * (1.f / 1024.f);
    float rs = rsqrtf(sq * (1.f / 1024.f) - mu * mu + 1e-5f);
    float o1a[4] = { o1.x, o1.y, o1.z, o1.w };
    float s2[4];
#pragma unroll
    for (int r = 0; r < 4; ++r) {
        float ffo = (s1[r] - mu) * rs * lnfg[tid * 4 + r] + lnfb[tid * 4 + r];
        s2[r] = o1a[r] + ffo;
    }
    float sum2 = s2[0] + s2[1] + s2[2] + s2[3];
    float sq2 = s2[0] * s2[0] + s2[1] * s2[1] + s2[2] * s2[2] + s2[3] * s2[3];
    block_reduce2(sum2, sq2);
    float mu2 = sum2 * (1.f / 1024.f);
    float rs2 = rsqrtf(sq2 * (1.f / 1024.f) - mu2 * mu2 + 1e-5f);
    float4 o;
    o.x = (s2[0] - mu2) * rs2 * ln2g[tid * 4 + 0] + ln2b[tid * 4 + 0];
    o.y = (s2[1] - mu2) * rs2 * ln2g[tid * 4 + 1] + ln2b[tid * 4 + 1];
    o.z = (s2[2] - mu2) * rs2 * ln2g[tid * 4 + 2] + ln2b[tid * 4 + 2];
    o.w = (s2[3] - mu2) * rs2 * ln2g[tid * 4 + 3] + ln2b[tid * 4 + 3];
    *(float4*)&out2[base] = o;
}

// ---------------- launcher ----------------
extern "C" void kernel_launch(void* const* d_in, const int* in_sizes, int n_in,
                              void* d_out, int out_size, void* d_ws, size_t ws_size,
                              hipStream_t stream) {
    const float* x    = (const float*)d_in[0];
    const float* wq   = (const float*)d_in[1];
    const float* bq   = (const float*)d_in[2];
    const float* wk   = (const float*)d_in[3];
    const float* bk   = (const float*)d_in[4];
    const float* wv   = (const float*)d_in[5];
    const float* bv   = (const float*)d_in[6];
    const float* wp   = (const float*)d_in[7];
    const float* bp   = (const float*)d_in[8];
    const float* w1   = (const float*)d_in[9];
    const float* b1   = (const float*)d_in[10];
    const float* w2   = (const float*)d_in[11];
    const float* b2   = (const float*)d_in[12];
    const float* ln1g = (const float*)d_in[13];
    const float* ln1b = (const float*)d_in[14];
    const float* lnfg = (const float*)d_in[15];
    const float* lnfb = (const float*)d_in[16];
    const float* ln2g = (const float*)d_in[17];
    const float* ln2b = (const float*)d_in[18];

    float* out2 = (float*)d_out;
    float* kv   = (float*)d_out + 4194304;   // Kc then Vc

    char* ws = (char*)d_ws;
    u16*   XB     = (u16*)  (ws + 0);          // 8 MB, reused as CAT
    u16*   CAT    = XB;
    u16*   WQKVT  = (u16*)  (ws + 8388608);    // 6 MB
    float* BQKV   = (float*)(ws + 14680064);   // 12 KB
    u16*   QKVB   = (u16*)  (ws + 14692352);   // 24 MB, reused as OUT1B after attn
    u16*   OUT1B  = QKVB;
    float* KTVF   = (float*)(ws + 39858176);   // 512 KB
    u16*   KTVT   = (u16*)  (ws + 40382464);   // 256 KB
    u16*   WPT    = (u16*)  (ws + 40644608);   // 2 MB
    float* OUTPRE = (float*)(ws + 42741760);   // 16 MB, reused as FF
    float* FF     = OUTPRE;
    float* OUT1F  = (float*)(ws + 59518976);   // 16 MB
    u16*   W1T    = (u16*)  (ws + 76296192);   // 8 MB
    u16*   W2T    = (u16*)  (ws + 84684800);   // 8 MB
    u16*   H1     = (u16*)  (ws + 93073408);   // 32 MB
    (void)ws_size; (void)in_sizes; (void)n_in; (void)out_size;

    hipMemsetAsync(KTVF, 0, 32 * 4096 * 4, stream);
    cast_x_kernel<<<4096, 256, 0, stream>>>(x, XB);
    prep_wqkv_kernel<<<12288, 256, 0, stream>>>(wq, wk, wv, bq, bk, bv, WQKVT, BQKV);
    transpose_cast<<<dim3(32, 32), 256, 0, stream>>>(wp, WPT, 1024, 1024);
    transpose_cast<<<dim3(128, 32), 256, 0, stream>>>(w1, W1T, 1024, 4096);
    transpose_cast<<<dim3(32, 128), 256, 0, stream>>>(w2, W2T, 4096, 1024);

    // G1: QKV = X @ Wqkv  (+Kc/Vc f32 side-out)
    gemm128<3><<<768, 256, 0, stream>>>(XB, WQKVT, BQKV, QKVB, nullptr, kv,
                                        4096, 3072, 1024, 1024, 1024, 3072);
    ktv_partial<<<dim3(8, 32), 256, 0, stream>>>(QKVB, KTVF);
    cast_ktv<<<512, 256, 0, stream>>>(KTVF, KTVT);
    attn_gemm<<<dim3(32, 32), 256, 0, stream>>>(QKVB, KTVT, CAT);

    // G3: out = cat @ wp + bp (f32)
    gemm128<1><<<256, 256, 0, stream>>>(CAT, WPT, bp, nullptr, OUTPRE, nullptr,
                                        4096, 1024, 1024, 1024, 1024, 1024);
    ln1_kernel<<<4096, 256, 0, stream>>>(x, OUTPRE, ln1g, ln1b, OUT1F, OUT1B);

    // G4: h1 = relu(out1 @ w1 + b1) (bf16)
    gemm128<2><<<1024, 256, 0, stream>>>(OUT1B, W1T, b1, H1, nullptr, nullptr,
                                         4096, 4096, 1024, 1024, 1024, 4096);
    // G5: ff = h1 @ w2 + b2 (f32)
    gemm128<1><<<256, 256, 0, stream>>>(H1, W2T, b2, nullptr, FF, nullptr,
                                        4096, 1024, 4096, 4096, 4096, 1024);
    lnf_kernel<<<4096, 256, 0, stream>>>(OUT1F, FF, lnfg, lnfb, ln2g, ln2b, out2);
}

// Round 2
// 275.026 us; speedup vs baseline: 1.1239x; 1.1239x over previous
//
#include <hip/hip_runtime.h>

typedef unsigned short u16;
typedef __attribute__((ext_vector_type(4))) float f32x4;
typedef __attribute__((ext_vector_type(8))) __bf16 bf16x8;
typedef __attribute__((ext_vector_type(8))) unsigned short u16x8;
typedef __attribute__((ext_vector_type(4))) unsigned short u16x4;

// ---------- scalar bf16 helpers ----------
__device__ __forceinline__ u16 f2b(float f) {
    unsigned int u = __builtin_bit_cast(unsigned int, f);
    u = (u + 0x7FFFu + ((u >> 16) & 1u)) >> 16;
    return (u16)u;
}
__device__ __forceinline__ float b2f(u16 h) {
    unsigned int u = ((unsigned int)h) << 16;
    return __builtin_bit_cast(float, u);
}

// async global->LDS, 16B per lane; LDS dest is wave-uniform base (+lane*16 by HW)
__device__ __forceinline__ void gload_lds16(const u16* g, u16* l) {
    __builtin_amdgcn_global_load_lds(
        (const __attribute__((address_space(1))) void*)g,
        (__attribute__((address_space(3))) void*)l,
        16, 0, 0);
}

__device__ __forceinline__ bf16x8 lds_frag(const u16* p) {
    u16x8 t = *(const u16x8*)p;
    return __builtin_bit_cast(bf16x8, t);
}

// ---------------- prep kernels ----------------
__global__ __launch_bounds__(256) void cast_x_kernel(const float* __restrict__ in,
                                                     u16* __restrict__ out) {
    int i = (blockIdx.x * 256 + threadIdx.x) * 4;
    float4 v = *(const float4*)&in[i];
    u16x4 o = { f2b(v.x), f2b(v.y), f2b(v.z), f2b(v.w) };
    *(u16x4*)&out[i] = o;
}

// WqkvT[n][d] = w_sel[h][d][e], n = sel*1024 + h*64 + e ; also bias vec [3072]
__global__ __launch_bounds__(256) void prep_wqkv_kernel(
    const float* __restrict__ wq, const float* __restrict__ wk, const float* __restrict__ wv,
    const float* __restrict__ bq, const float* __restrict__ bk, const float* __restrict__ bv,
    u16* __restrict__ WT, float* __restrict__ BI) {
    int idx = blockIdx.x * 256 + threadIdx.x;     // < 3072*1024
    int n = idx >> 10, d = idx & 1023;
    int sel = n >> 10, hh = (n & 1023) >> 6, e = n & 63;
    const float* w = (sel == 0) ? wq : (sel == 1) ? wk : wv;
    WT[idx] = f2b(w[(hh * 1024 + d) * 64 + e]);
    if (idx < 3072) {
        const float* bb = (idx < 1024) ? bq : (idx < 2048) ? bk : bv;
        BI[idx] = bb[((idx & 1023) >> 6) * 64 + (idx & 63)];
    }
}

// out[c][r] = (bf16) in[r][c]   (in: [R][C] f32)
__global__ __launch_bounds__(256) void transpose_cast(const float* __restrict__ in,
                                                      u16* __restrict__ out, int R, int C) {
    __shared__ float tile[32][33];
    int tx = threadIdx.x & 31, ty = threadIdx.x >> 5;   // 32 x 8
    int r0 = blockIdx.y * 32, c0 = blockIdx.x * 32;
#pragma unroll
    for (int i = 0; i < 32; i += 8)
        tile[ty + i][tx] = in[(long)(r0 + ty + i) * C + c0 + tx];
    __syncthreads();
#pragma unroll
    for (int i = 0; i < 32; i += 8)
        out[(long)(c0 + ty + i) * R + r0 + tx] = f2b(tile[tx][ty + i]);
}

// ---------------- main 128x128 bf16 GEMM (m97 structure) ----------------
// C[M,N] = A[M,K] @ BT[N,K]^T  (+bias[col]).
// MODE 2: relu, bf16 out to Cb (+bias). MODE 3: bf16 out to Cb (+bias) + f32 side
// write of cols>=1024 into KV. MODE 4: split-K f32 partial (NO bias) to p{0,1,2}
// selected by sk = blockIdx.x / (mt*nt); k range [sk*kchunk, min(K, +kchunk)).
template <int MODE>
__global__ __launch_bounds__(256) void gemm128(
    const u16* __restrict__ A, const u16* __restrict__ BT, const float* __restrict__ bias,
    u16* __restrict__ Cb, float* __restrict__ Cf, float* __restrict__ KV,
    float* __restrict__ P1, float* __restrict__ P2,
    int M, int N, int K, int lda, int ldb, int ldc, int kchunk) {
    __shared__ __align__(16) u16 As[128 * 32];
    __shared__ __align__(16) u16 Bs[128 * 32];
    const int tid = threadIdx.x;
    const int wid = tid >> 6, lane = tid & 63;
    const int ntile = N >> 7;
    int bid = blockIdx.x;
    int kb = 0, ke = K;
    float* Pout = Cf;
    if (MODE == 4) {
        const int tiles = (M >> 7) * ntile;
        int sk = bid / tiles;
        bid -= sk * tiles;
        kb = sk * kchunk;
        ke = kb + kchunk < K ? kb + kchunk : K;
        Pout = (sk == 0) ? Cf : (sk == 1) ? P1 : P2;
    }
    const int bi = bid / ntile, bj = bid % ntile;
    const int brow = bi * 128, bcol = bj * 128;
    const int wr = wid >> 1, wc = wid & 1;

    f32x4 acc[4][4] = {};
    const u16* Abase = A + (long)brow * lda;
    const u16* Bbase = BT + (long)bcol * ldb;

    for (int k0 = kb; k0 < ke; k0 += 32) {
#pragma unroll
        for (int i = 0; i < 2; ++i) {
            int c = i * 256 + tid;               // chunk: row=c>>2, kc=c&3 (8 elems each)
            gload_lds16(Abase + (c >> 2) * lda + k0 + (c & 3) * 8, &As[(i * 256 + wid * 64) * 8]);
            gload_lds16(Bbase + (c >> 2) * ldb + k0 + (c & 3) * 8, &Bs[(i * 256 + wid * 64) * 8]);
        }
        __syncthreads();
        bf16x8 af[4], bfr[4];
#pragma unroll
        for (int m = 0; m < 4; ++m)
            af[m] = lds_frag(&As[(wr * 64 + m * 16 + (lane & 15)) * 32 + (lane >> 4) * 8]);
#pragma unroll
        for (int n = 0; n < 4; ++n)
            bfr[n] = lds_frag(&Bs[(wc * 64 + n * 16 + (lane & 15)) * 32 + (lane >> 4) * 8]);
#pragma unroll
        for (int m = 0; m < 4; ++m)
#pragma unroll
            for (int n = 0; n < 4; ++n)
                acc[m][n] = __builtin_amdgcn_mfma_f32_16x16x32_bf16(af[m], bfr[n], acc[m][n], 0, 0, 0);
        __syncthreads();
    }

#pragma unroll
    for (int m = 0; m < 4; ++m)
#pragma unroll
        for (int n = 0; n < 4; ++n) {
            int col = bcol + wc * 64 + n * 16 + (lane & 15);
            float bv = (MODE == 4) ? 0.f : bias[col];
#pragma unroll
            for (int r = 0; r < 4; ++r) {
                int row = brow + wr * 64 + m * 16 + (lane >> 4) * 4 + r;
                float v = acc[m][n][r] + bv;
                if (MODE == 2) v = v > 0.f ? v : 0.f;
                if (MODE == 4) {
                    Pout[(long)row * ldc + col] = v;
                } else {
                    Cb[(long)row * ldc + col] = f2b(v);
                    if (MODE == 3 && col >= 1024) {
                        int c = col - 1024;
                        KV[(long)(c >> 10) * 4194304 + (long)row * 1024 + (c & 1023)] = v;
                    }
                }
            }
        }
}

// ---------------- K^T V partial sums (t-chunked, f32 atomics) ----------------
__global__ __launch_bounds__(256) void ktv_partial(const u16* __restrict__ QKVB,
                                                   float* __restrict__ KTVF) {
    __shared__ __align__(16) u16 Ks[64 * 64];
    __shared__ __align__(16) u16 Vs[64 * 64];
    int tid = threadIdx.x;
    int tc = blockIdx.x, bh = blockIdx.y;
    int b = bh >> 4, h = bh & 15;
    int j = tid & 63, i0 = (tid >> 6) * 16;
    float acc[16] = {};
    for (int st = 0; st < 4; ++st) {
        int t0 = tc * 256 + st * 64;
        __syncthreads();
#pragma unroll
        for (int i = 0; i < 2; ++i) {
            int c = i * 256 + tid;               // row=c>>3, ch=c&7
            long base = (long)(b * 2048 + t0 + (c >> 3)) * 3072 + h * 64 + (c & 7) * 8;
            *(u16x8*)&Ks[c * 8] = *(const u16x8*)&QKVB[base + 1024];
            *(u16x8*)&Vs[c * 8] = *(const u16x8*)&QKVB[base + 2048];
        }
        __syncthreads();
        for (int tt = 0; tt < 64; ++tt) {
            float vj = b2f(Vs[tt * 64 + j]);
            u16x8 k0 = *(const u16x8*)&Ks[tt * 64 + i0];
            u16x8 k1 = *(const u16x8*)&Ks[tt * 64 + i0 + 8];
#pragma unroll
            for (int r = 0; r < 8; ++r) acc[r] += b2f(k0[r]) * vj;
#pragma unroll
            for (int r = 0; r < 8; ++r) acc[r + 8] += b2f(k1[r]) * vj;
        }
    }
#pragma unroll
    for (int r = 0; r < 16; ++r)
        atomicAdd(&KTVF[bh * 4096 + (i0 + r) * 64 + j], acc[r]);
}

// KTVT[bh][n][k] = KTVF[bh][k][n] * 0.125 (fold 1/sqrt(64))
__global__ __launch_bounds__(256) void cast_ktv(const float* __restrict__ KTVF,
                                                u16* __restrict__ KTVT) {
    int idx = blockIdx.x * 256 + threadIdx.x;   // < 32*4096
    int bh = idx >> 12, r = idx & 4095;
    int n = r >> 6, k = r & 63;
    KTVT[idx] = f2b(KTVF[bh * 4096 + k * 64 + n] * 0.125f);
}

// ---------------- batched attn GEMM: cat[t, h*64+e'] = Q[t,:] @ KTVT[e',:] ----------------
__global__ __launch_bounds__(256) void attn_gemm(const u16* __restrict__ QKVB,
                                                 const u16* __restrict__ KTVT,
                                                 u16* __restrict__ cat) {
    __shared__ __align__(16) u16 Qs[64 * 64];
    __shared__ __align__(16) u16 Bs[64 * 64];
    int tid = threadIdx.x, wid = tid >> 6, lane = tid & 63;
    int rt = blockIdx.x, bh = blockIdx.y;
    int b = bh >> 4, h = bh & 15;
    long qbase = (long)(b * 2048 + rt * 64) * 3072 + h * 64;
#pragma unroll
    for (int i = 0; i < 2; ++i) {
        int c = i * 256 + tid;                   // row=c>>3, ch=c&7
        gload_lds16(QKVB + qbase + (c >> 3) * 3072 + (c & 7) * 8, &Qs[(i * 256 + wid * 64) * 8]);
        gload_lds16(KTVT + bh * 4096 + c * 8, &Bs[(i * 256 + wid * 64) * 8]);
    }
    __syncthreads();
    f32x4 acc[4] = {};
#pragma unroll
    for (int kk = 0; kk < 2; ++kk) {
        bf16x8 a = lds_frag(&Qs[(wid * 16 + (lane & 15)) * 64 + kk * 32 + (lane >> 4) * 8]);
#pragma unroll
        for (int n = 0; n < 4; ++n) {
            bf16x8 bb = lds_frag(&Bs[(n * 16 + (lane & 15)) * 64 + kk * 32 + (lane >> 4) * 8]);
            acc[n] = __builtin_amdgcn_mfma_f32_16x16x32_bf16(a, bb, acc[n], 0, 0, 0);
        }
    }
#pragma unroll
    for (int n = 0; n < 4; ++n)
#pragma unroll
        for (int r = 0; r < 4; ++r) {
            int row = rt * 64 + wid * 16 + (lane >> 4) * 4 + r;   // t within batch
            int col = h * 64 + n * 16 + (lane & 15);
            cat[(long)(b * 2048 + row) * 1024 + col] = f2b(acc[n][r]);
        }
}

// ---------------- layernorm kernels ----------------
__device__ __forceinline__ void block_reduce2(float& a, float& b) {
    __syncthreads();
#pragma unroll
    for (int off = 32; off; off >>= 1) {
        a += __shfl_down(a, off);
        b += __shfl_down(b, off);
    }
    __shared__ float sa[4], sb[4];
    int wid = threadIdx.x >> 6, lane = threadIdx.x & 63;
    if (lane == 0) { sa[wid] = a; sb[wid] = b; }
    __syncthreads();
    a = sa[0] + sa[1] + sa[2] + sa[3];
    b = sb[0] + sb[1] + sb[2] + sb[3];
}

// out1 = LN(x + (p0+p1+p2 + bp)) ; write f32 + bf16
__global__ __launch_bounds__(256) void ln1_kernel(
    const float* __restrict__ x,
    const float* __restrict__ p0, const float* __restrict__ p1, const float* __restrict__ p2,
    const float* __restrict__ bp,
    const float* __restrict__ g, const float* __restrict__ bt,
    float* __restrict__ out1f, u16* __restrict__ out1b) {
    int row = blockIdx.x, tid = threadIdx.x;
    long base = (long)row * 1024 + tid * 4;
    float4 xv = *(const float4*)&x[base];
    float4 a0 = *(const float4*)&p0[base];
    float4 a1 = *(const float4*)&p1[base];
    float4 a2 = *(const float4*)&p2[base];
    float4 bb = *(const float4*)&bp[tid * 4];
    float s[4] = { xv.x + a0.x + a1.x + a2.x + bb.x,
                   xv.y + a0.y + a1.y + a2.y + bb.y,
                   xv.z + a0.z + a1.z + a2.z + bb.z,
                   xv.w + a0.w + a1.w + a2.w + bb.w };
    float sum = s[0] + s[1] + s[2] + s[3];
    float sq = s[0] * s[0] + s[1] * s[1] + s[2] * s[2] + s[3] * s[3];
    block_reduce2(sum, sq);
    float mu = sum * (1.f / 1024.f);
    float var = sq * (1.f / 1024.f) - mu * mu;
    float rs = rsqrtf(var + 1e-5f);
    float o0 = (s[0] - mu) * rs * g[tid * 4 + 0] + bt[tid * 4 + 0];
    float o1 = (s[1] - mu) * rs * g[tid * 4 + 1] + bt[tid * 4 + 1];
    float o2 = (s[2] - mu) * rs * g[tid * 4 + 2] + bt[tid * 4 + 2];
    float o3 = (s[3] - mu) * rs * g[tid * 4 + 3] + bt[tid * 4 + 3];
    float4 of; of.x = o0; of.y = o1; of.z = o2; of.w = o3;
    u16x4 ob = (u16x4){ f2b(o0), f2b(o1), f2b(o2), f2b(o3) };
    *(float4*)&out1f[base] = of;
    *(u16x4*)&out1b[base] = ob;
}

// ff = q0+q1+q2+b2 ; ffo = LN(out1+ff); out2 = LN(out1+ffo) -> d_out
__global__ __launch_bounds__(256) void lnf_kernel(
    const float* __restrict__ out1f,
    const float* __restrict__ q0, const float* __restrict__ q1, const float* __restrict__ q2,
    const float* __restrict__ b2,
    const float* __restrict__ lnfg, const float* __restrict__ lnfb,
    const float* __restrict__ ln2g, const float* __restrict__ ln2b,
    float* __restrict__ out2) {
    int row = blockIdx.x, tid = threadIdx.x;
    long base = (long)row * 1024 + tid * 4;
    float4 o1 = *(const float4*)&out1f[base];
    float4 a0 = *(const float4*)&q0[base];
    float4 a1 = *(const float4*)&q1[base];
    float4 a2 = *(const float4*)&q2[base];
    float4 bb = *(const float4*)&b2[tid * 4];
    float s1[4] = { o1.x + a0.x + a1.x + a2.x + bb.x,
                    o1.y + a0.y + a1.y + a2.y + bb.y,
                    o1.z + a0.z + a1.z + a2.z + bb.z,
                    o1.w + a0.w + a1.w + a2.w + bb.w };
    float sum = s1[0] + s1[1] + s1[2] + s1[3];
    float sq = s1[0] * s1[0] + s1[1] * s1[1] + s1[2] * s1[2] + s1[3] * s1[3];
    block_reduce2(sum, sq);
    float mu = sum * (1.f / 1024.f);
    float rs = rsqrtf(sq * (1.f / 1024.f) - mu * mu + 1e-5f);
    float o1a[4] = { o1.x, o1.y, o1.z, o1.w };
    float s2[4];
#pragma unroll
    for (int r = 0; r < 4; ++r) {
        float ffo = (s1[r] - mu) * rs * lnfg[tid * 4 + r] + lnfb[tid * 4 + r];
        s2[r] = o1a[r] + ffo;
    }
    float sum2 = s2[0] + s2[1] + s2[2] + s2[3];
    float sq2 = s2[0] * s2[0] + s2[1] * s2[1] + s2[2] * s2[2] + s2[3] * s2[3];
    block_reduce2(sum2, sq2);
    float mu2 = sum2 * (1.f / 1024.f);
    float rs2 = rsqrtf(sq2 * (1.f / 1024.f) - mu2 * mu2 + 1e-5f);
    float4 o;
    o.x = (s2[0] - mu2) * rs2 * ln2g[tid * 4 + 0] + ln2b[tid * 4 + 0];
    o.y = (s2[1] - mu2) * rs2 * ln2g[tid * 4 + 1] + ln2b[tid * 4 + 1];
    o.z = (s2[2] - mu2) * rs2 * ln2g[tid * 4 + 2] + ln2b[tid * 4 + 2];
    o.w = (s2[3] - mu2) * rs2 * ln2g[tid * 4 + 3] + ln2b[tid * 4 + 3];
    *(float4*)&out2[base] = o;
}

// ---------------- launcher ----------------
extern "C" void kernel_launch(void* const* d_in, const int* in_sizes, int n_in,
                              void* d_out, int out_size, void* d_ws, size_t ws_size,
                              hipStream_t stream) {
    const float* x    = (const float*)d_in[0];
    const float* wq   = (const float*)d_in[1];
    const float* bq   = (const float*)d_in[2];
    const float* wk   = (const float*)d_in[3];
    const float* bk   = (const float*)d_in[4];
    const float* wv   = (const float*)d_in[5];
    const float* bv   = (const float*)d_in[6];
    const float* wp   = (const float*)d_in[7];
    const float* bp   = (const float*)d_in[8];
    const float* w1   = (const float*)d_in[9];
    const float* b1   = (const float*)d_in[10];
    const float* w2   = (const float*)d_in[11];
    const float* b2   = (const float*)d_in[12];
    const float* ln1g = (const float*)d_in[13];
    const float* ln1b = (const float*)d_in[14];
    const float* lnfg = (const float*)d_in[15];
    const float* lnfb = (const float*)d_in[16];
    const float* ln2g = (const float*)d_in[17];
    const float* ln2b = (const float*)d_in[18];

    float* out2 = (float*)d_out;
    float* kv   = (float*)d_out + 4194304;   // Kc then Vc

    // workspace layout (bytes). Liveness chain documented per region.
    char* ws = (char*)d_ws;
    u16*   XB     = (u16*)  (ws + 0);          // 8 MB  x bf16 (dead after G1); reused as CAT (dead after G3)
    u16*   CAT    = XB;
    u16*   WQKVT  = (u16*)  (ws + 8388608);    // 6 MB  (dead after G1)
    float* BQKV   = (float*)(ws + 14680064);   // 12 KB (dead after G1)
    u16*   WPT    = (u16*)  (ws + 14692352);   // 2 MB  (dead after G3)
    u16*   W1T    = (u16*)  (ws + 16789504);   // 8 MB  (dead after G4)
    u16*   W2T    = (u16*)  (ws + 25178112);   // 8 MB  (dead after G5)
    float* KTVF   = (float*)(ws + 33566720);   // 512 KB
    u16*   KTVT   = (u16*)  (ws + 34091008);   // 256 KB
    u16*   QKVB   = (u16*)  (ws + 34353152);   // 24 MB (dead after attn_gemm); reused as OUT1B (dead after G4)
    u16*   OUT1B  = QKVB;
    float* G3P0   = (float*)(ws + 59518976);   // 16 MB G3 partial0 (dead after ln1); reused as G5 partial2
    float* OUT1F  = (float*)(ws + 76296192);   // 16 MB (live to lnf)
    float* H1area = (float*)(ws + 93073408);   // 32 MB: G3 partials1,2 (dead after ln1) then H1 bf16 (dead after G5)
    float* G3P1   = H1area;
    float* G3P2   = (float*)(ws + 109850624);
    u16*   H1     = (u16*)  (ws + 93073408);
    float* G5P0   = (float*)(ws + 0);          // 16 MB over XB/WQKVT/BQKV/WPT (all dead after G4)
    float* G5P1   = (float*)(ws + 34353152);   // 16 MB over OUT1B (dead after G4)
    float* G5P2   = G3P0;                      // 16 MB over G3P0 (dead after ln1)
    (void)ws_size; (void)in_sizes; (void)n_in; (void)out_size;

    hipMemsetAsync(KTVF, 0, 32 * 4096 * 4, stream);
    cast_x_kernel<<<4096, 256, 0, stream>>>(x, XB);
    prep_wqkv_kernel<<<12288, 256, 0, stream>>>(wq, wk, wv, bq, bk, bv, WQKVT, BQKV);
    transpose_cast<<<dim3(32, 32), 256, 0, stream>>>(wp, WPT, 1024, 1024);
    transpose_cast<<<dim3(128, 32), 256, 0, stream>>>(w1, W1T, 1024, 4096);
    transpose_cast<<<dim3(32, 128), 256, 0, stream>>>(w2, W2T, 4096, 1024);

    // G1: QKV = X @ Wqkv  (+Kc/Vc f32 side-out)
    gemm128<3><<<768, 256, 0, stream>>>(XB, WQKVT, BQKV, QKVB, nullptr, kv, nullptr, nullptr,
                                        4096, 3072, 1024, 1024, 1024, 3072, 0);
    ktv_partial<<<dim3(8, 32), 256, 0, stream>>>(QKVB, KTVF);
    cast_ktv<<<512, 256, 0, stream>>>(KTVF, KTVT);
    attn_gemm<<<dim3(32, 32), 256, 0, stream>>>(QKVB, KTVT, CAT);

    // G3: out = cat @ wp (split-K x3, f32 partials; bias folded into ln1)
    gemm128<4><<<768, 256, 0, stream>>>(CAT, WPT, nullptr, nullptr, G3P0, nullptr, G3P1, G3P2,
                                        4096, 1024, 1024, 1024, 1024, 1024, 352);
    ln1_kernel<<<4096, 256, 0, stream>>>(x, G3P0, G3P1, G3P2, bp, ln1g, ln1b, OUT1F, OUT1B);

    // G4: h1 = relu(out1 @ w1 + b1) (bf16)
    gemm128<2><<<1024, 256, 0, stream>>>(OUT1B, W1T, b1, H1, nullptr, nullptr, nullptr, nullptr,
                                         4096, 4096, 1024, 1024, 1024, 4096, 0);
    // G5: ff = h1 @ w2 (split-K x3, f32 partials; bias folded into lnf)
    gemm128<4><<<768, 256, 0, stream>>>(H1, W2T, nullptr, nullptr, G5P0, nullptr, G5P1, G5P2,
                                        4096, 1024, 4096, 4096, 4096, 1024, 1376);
    lnf_kernel<<<4096, 256, 0, stream>>>(OUT1F, G5P0, G5P1, G5P2, b2, lnfg, lnfb, ln2g, ln2b, out2);
}

// Round 3
// 238.609 us; speedup vs baseline: 1.2954x; 1.1526x over previous
//
#include <hip/hip_runtime.h>

typedef unsigned short u16;
typedef __attribute__((ext_vector_type(4))) float f32x4;
typedef __attribute__((ext_vector_type(8))) __bf16 bf16x8;
typedef __attribute__((ext_vector_type(8))) unsigned short u16x8;
typedef __attribute__((ext_vector_type(4))) unsigned short u16x4;

// ---------- scalar bf16 helpers ----------
__device__ __forceinline__ u16 f2b(float f) {
    unsigned int u = __builtin_bit_cast(unsigned int, f);
    u = (u + 0x7FFFu + ((u >> 16) & 1u)) >> 16;
    return (u16)u;
}
__device__ __forceinline__ float b2f(u16 h) {
    unsigned int u = ((unsigned int)h) << 16;
    return __builtin_bit_cast(float, u);
}

// async global->LDS, 16B per lane; LDS dest is wave-uniform base (+lane*16 by HW)
__device__ __forceinline__ void gload_lds16(const u16* g, u16* l) {
    __builtin_amdgcn_global_load_lds(
        (const __attribute__((address_space(1))) void*)g,
        (__attribute__((address_space(3))) void*)l,
        16, 0, 0);
}

__device__ __forceinline__ bf16x8 lds_frag(const u16* p) {
    u16x8 t = *(const u16x8*)p;
    return __builtin_bit_cast(bf16x8, t);
}

#define FENCE asm volatile("" ::: "memory")
#define BARRIER do { FENCE; __builtin_amdgcn_s_barrier(); FENCE; \
                     __builtin_amdgcn_sched_barrier(0); } while (0)
#define WAIT_VM8 do { asm volatile("s_waitcnt vmcnt(8)" ::: "memory"); \
                      __builtin_amdgcn_sched_barrier(0); } while (0)
#define WAIT_VM0 do { asm volatile("s_waitcnt vmcnt(0)" ::: "memory"); \
                      __builtin_amdgcn_sched_barrier(0); } while (0)

// ---------------- prep kernels ----------------
__global__ __launch_bounds__(256) void cast_x_kernel(const float* __restrict__ in,
                                                     u16* __restrict__ out) {
    int i = (blockIdx.x * 256 + threadIdx.x) * 4;
    float4 v = *(const float4*)&in[i];
    u16x4 o = { f2b(v.x), f2b(v.y), f2b(v.z), f2b(v.w) };
    *(u16x4*)&out[i] = o;
}

// WqkvT[n][d] = w_sel[h][d][e], n = sel*1024 + h*64 + e ; also bias vec [3072]
__global__ __launch_bounds__(256) void prep_wqkv_kernel(
    const float* __restrict__ wq, const float* __restrict__ wk, const float* __restrict__ wv,
    const float* __restrict__ bq, const float* __restrict__ bk, const float* __restrict__ bv,
    u16* __restrict__ WT, float* __restrict__ BI) {
    int idx = blockIdx.x * 256 + threadIdx.x;     // < 3072*1024
    int n = idx >> 10, d = idx & 1023;
    int sel = n >> 10, hh = (n & 1023) >> 6, e = n & 63;
    const float* w = (sel == 0) ? wq : (sel == 1) ? wk : wv;
    WT[idx] = f2b(w[(hh * 1024 + d) * 64 + e]);
    if (idx < 3072) {
        const float* bb = (idx < 1024) ? bq : (idx < 2048) ? bk : bv;
        BI[idx] = bb[((idx & 1023) >> 6) * 64 + (idx & 63)];
    }
}

// out[c][r] = (bf16) in[r][c]   (in: [R][C] f32)
__global__ __launch_bounds__(256) void transpose_cast(const float* __restrict__ in,
                                                      u16* __restrict__ out, int R, int C) {
    __shared__ float tile[32][33];
    int tx = threadIdx.x & 31, ty = threadIdx.x >> 5;   // 32 x 8
    int r0 = blockIdx.y * 32, c0 = blockIdx.x * 32;
#pragma unroll
    for (int i = 0; i < 32; i += 8)
        tile[ty + i][tx] = in[(long)(r0 + ty + i) * C + c0 + tx];
    __syncthreads();
#pragma unroll
    for (int i = 0; i < 32; i += 8)
        out[(long)(c0 + ty + i) * R + r0 + tx] = f2b(tile[tx][ty + i]);
}

// ---------------- 256x256 8-wave BK=64 GEMM, counted-vmcnt pipeline ----------------
// C[M,N] = A[M,K] @ BT[N,K]^T.
// MODE 1: +bias, bf16 out to Cb, f32 side-write cols>=1024 into KV (G1).
// MODE 2: +bias, relu, bf16 out to Cb (G4).
// MODE 4: split-K bf16 partials (no bias) to Q0..Q3 by sk (G5).
// LDS layout per half: [256 rows][64 k] bf16, row=128B, byte-swizzle
// col_byte ^= (row&7)<<4; staging inverse-swizzles the GLOBAL source (rule #21).
template <int MODE>
__global__ __launch_bounds__(512, 2) void gemm256(
    const u16* __restrict__ A, const u16* __restrict__ BT, const float* __restrict__ bias,
    u16* __restrict__ Cb, float* __restrict__ KV,
    u16* __restrict__ Q0, u16* __restrict__ Q1, u16* __restrict__ Q2, u16* __restrict__ Q3,
    int M, int N, int K, int lda, int ldb, int ldc, int kchunk) {
    __shared__ __align__(16) u16 As[2][16384];
    __shared__ __align__(16) u16 Bs[2][16384];
    const int tid = threadIdx.x;
    const int lane = tid & 63;
    const int wid = tid >> 6;
    const int wr = wid >> 2, wc = wid & 3;
    const int ntile = N >> 8;
    int bid = blockIdx.x;
    int kb = 0, ksz = K;
    u16* Pout = Q0;
    if (MODE == 4) {
        int tiles = (M >> 8) * ntile;
        int sk = bid / tiles; bid -= sk * tiles;
        kb = sk * kchunk;
        int rem = K - kb; ksz = rem < kchunk ? rem : kchunk;
        Pout = (sk == 0) ? Q0 : (sk == 1) ? Q1 : (sk == 2) ? Q2 : Q3;
    }
    const int bi = bid / ntile, bj = bid % ntile;
    const int brow = bi << 8, bcol = bj << 8;
    const int nt = ksz >> 6;   // BK=64 tiles

    // ---- staging addressing (inverse-swizzled global source, linear LDS dest)
    const int srow = tid >> 3;                        // 0..63 (+j*64)
    const int scol = ((tid & 7) ^ (srow & 7)) << 3;   // element offset in row
    const u16* ag = A + (long)(brow + srow) * lda + kb + scol;
    const u16* bg = BT + (long)(bcol + srow) * ldb + kb + scol;
    const long a64 = (long)lda << 6, b64 = (long)ldb << 6;
    const int sdst = tid << 3;                        // u16 elems (+j*4096)

    auto STAGE = [&](int buf, int t) {
        const u16* a_ = ag + ((long)t << 6);
        const u16* b_ = bg + ((long)t << 6);
#pragma unroll
        for (int j = 0; j < 4; ++j) {
            gload_lds16(a_ + j * a64, &As[buf][j * 4096 + sdst]);
            gload_lds16(b_ + j * b64, &Bs[buf][j * 4096 + sdst]);
        }
    };

    f32x4 acc[8][4] = {};

    // ---- fragment read addressing (swizzled)
    const int ln15 = lane & 15;
    const int eoff = (((lane >> 4) << 3) ^ ((lane & 7) << 3));  // elem offset, ks=0
    const int arow0 = (wr << 7) + ln15;
    const int brow0 = (wc << 6) + ln15;

    // ---- prologue: fill both buffers, wait tile0 only
    STAGE(0, 0);
    if (nt > 1) { STAGE(1, 1); WAIT_VM8; } else { WAIT_VM0; }
    BARRIER;
    int cur = 0;

    for (int t = 0; t < nt; ++t) {
        const u16* Ac = As[cur];
        const u16* Bc = Bs[cur];
        bf16x8 bfr[4][2];
#pragma unroll
        for (int n = 0; n < 4; ++n) {
            int base = (brow0 + (n << 4)) << 6;
            bfr[n][0] = lds_frag(&Bc[base + eoff]);
            bfr[n][1] = lds_frag(&Bc[base + (eoff ^ 32)]);
        }
#pragma unroll
        for (int mh = 0; mh < 2; ++mh) {
            bf16x8 af[4][2];
#pragma unroll
            for (int m4 = 0; m4 < 4; ++m4) {
                int base = (arow0 + ((mh * 4 + m4) << 4)) << 6;
                af[m4][0] = lds_frag(&Ac[base + eoff]);
                af[m4][1] = lds_frag(&Ac[base + (eoff ^ 32)]);
            }
#pragma unroll
            for (int m4 = 0; m4 < 4; ++m4)
#pragma unroll
                for (int n = 0; n < 4; ++n) {
                    acc[mh * 4 + m4][n] = __builtin_amdgcn_mfma_f32_16x16x32_bf16(
                        af[m4][0], bfr[n][0], acc[mh * 4 + m4][n], 0, 0, 0);
                    acc[mh * 4 + m4][n] = __builtin_amdgcn_mfma_f32_16x16x32_bf16(
                        af[m4][1], bfr[n][1], acc[mh * 4 + m4][n], 0, 0, 0);
                }
        }
        if (t + 1 < nt) {
            BARRIER;                       // all waves done reading buf[cur]
            if (t + 2 < nt) { STAGE(cur, t + 2); WAIT_VM8; }  // t+1 landed, 8 in flight
            else           { WAIT_VM0; }
            BARRIER;                       // tile t+1 visible to all waves
            cur ^= 1;
        }
    }

    // ---- epilogue
#pragma unroll
    for (int m = 0; m < 8; ++m) {
        int row = brow + (wr << 7) + (m << 4) + ((lane >> 4) << 2);
#pragma unroll
        for (int n = 0; n < 4; ++n) {
            int col = bcol + (wc << 6) + (n << 4) + ln15;
            float bv = (MODE == 4) ? 0.f : bias[col];
#pragma unroll
            for (int r = 0; r < 4; ++r) {
                float v = acc[m][n][r] + bv;
                long off = (long)(row + r) * ldc + col;
                if (MODE == 2) { v = v > 0.f ? v : 0.f; Cb[off] = f2b(v); }
                if (MODE == 1) {
                    Cb[off] = f2b(v);
                    if (col >= 1024) {
                        int c = col - 1024;
                        KV[(long)(c >> 10) * 4194304 + (long)(row + r) * 1024 + (c & 1023)] = v;
                    }
                }
                if (MODE == 4) Pout[off] = f2b(v);
            }
        }
    }
}

// ---------------- 128x128 GEMM (m97 structure) — kept for G3 split-K ----------------
template <int MODE>
__global__ __launch_bounds__(256) void gemm128(
    const u16* __restrict__ A, const u16* __restrict__ BT, const float* __restrict__ bias,
    u16* __restrict__ Cb, float* __restrict__ Cf, float* __restrict__ KV,
    float* __restrict__ P1, float* __restrict__ P2,
    int M, int N, int K, int lda, int ldb, int ldc, int kchunk) {
    __shared__ __align__(16) u16 As[128 * 32];
    __shared__ __align__(16) u16 Bs[128 * 32];
    const int tid = threadIdx.x;
    const int wid = tid >> 6, lane = tid & 63;
    const int ntile = N >> 7;
    int bid = blockIdx.x;
    int kb = 0, ke = K;
    float* Pout = Cf;
    if (MODE == 4) {
        const int tiles = (M >> 7) * ntile;
        int sk = bid / tiles;
        bid -= sk * tiles;
        kb = sk * kchunk;
        ke = kb + kchunk < K ? kb + kchunk : K;
        Pout = (sk == 0) ? Cf : (sk == 1) ? P1 : P2;
    }
    const int bi = bid / ntile, bj = bid % ntile;
    const int brow = bi * 128, bcol = bj * 128;
    const int wr = wid >> 1, wc = wid & 1;

    f32x4 acc[4][4] = {};
    const u16* Abase = A + (long)brow * lda;
    const u16* Bbase = BT + (long)bcol * ldb;

    for (int k0 = kb; k0 < ke; k0 += 32) {
#pragma unroll
        for (int i = 0; i < 2; ++i) {
            int c = i * 256 + tid;
            gload_lds16(Abase + (c >> 2) * lda + k0 + (c & 3) * 8, &As[(i * 256 + wid * 64) * 8]);
            gload_lds16(Bbase + (c >> 2) * ldb + k0 + (c & 3) * 8, &Bs[(i * 256 + wid * 64) * 8]);
        }
        __syncthreads();
        bf16x8 af[4], bfr[4];
#pragma unroll
        for (int m = 0; m < 4; ++m)
            af[m] = lds_frag(&As[(wr * 64 + m * 16 + (lane & 15)) * 32 + (lane >> 4) * 8]);
#pragma unroll
        for (int n = 0; n < 4; ++n)
            bfr[n] = lds_frag(&Bs[(wc * 64 + n * 16 + (lane & 15)) * 32 + (lane >> 4) * 8]);
#pragma unroll
        for (int m = 0; m < 4; ++m)
#pragma unroll
            for (int n = 0; n < 4; ++n)
                acc[m][n] = __builtin_amdgcn_mfma_f32_16x16x32_bf16(af[m], bfr[n], acc[m][n], 0, 0, 0);
        __syncthreads();
    }

#pragma unroll
    for (int m = 0; m < 4; ++m)
#pragma unroll
        for (int n = 0; n < 4; ++n) {
            int col = bcol + wc * 64 + n * 16 + (lane & 15);
#pragma unroll
            for (int r = 0; r < 4; ++r) {
                int row = brow + wr * 64 + m * 16 + (lane >> 4) * 4 + r;
                float v = acc[m][n][r];
                if (MODE == 4) Pout[(long)row * ldc + col] = v;
            }
        }
}

// ---------------- K^T V partial sums (t-chunked, f32 atomics) ----------------
__global__ __launch_bounds__(256) void ktv_partial(const u16* __restrict__ QKVB,
                                                   float* __restrict__ KTVF) {
    __shared__ __align__(16) u16 Ks[64 * 64];
    __shared__ __align__(16) u16 Vs[64 * 64];
    int tid = threadIdx.x;
    int tc = blockIdx.x, bh = blockIdx.y;
    int b = bh >> 4, h = bh & 15;
    int j = tid & 63, i0 = (tid >> 6) * 16;
    float acc[16] = {};
    for (int st = 0; st < 4; ++st) {
        int t0 = tc * 256 + st * 64;
        __syncthreads();
#pragma unroll
        for (int i = 0; i < 2; ++i) {
            int c = i * 256 + tid;
            long base = (long)(b * 2048 + t0 + (c >> 3)) * 3072 + h * 64 + (c & 7) * 8;
            *(u16x8*)&Ks[c * 8] = *(const u16x8*)&QKVB[base + 1024];
            *(u16x8*)&Vs[c * 8] = *(const u16x8*)&QKVB[base + 2048];
        }
        __syncthreads();
        for (int tt = 0; tt < 64; ++tt) {
            float vj = b2f(Vs[tt * 64 + j]);
            u16x8 k0 = *(const u16x8*)&Ks[tt * 64 + i0];
            u16x8 k1 = *(const u16x8*)&Ks[tt * 64 + i0 + 8];
#pragma unroll
            for (int r = 0; r < 8; ++r) acc[r] += b2f(k0[r]) * vj;
#pragma unroll
            for (int r = 0; r < 8; ++r) acc[r + 8] += b2f(k1[r]) * vj;
        }
    }
#pragma unroll
    for (int r = 0; r < 16; ++r)
        atomicAdd(&KTVF[bh * 4096 + (i0 + r) * 64 + j], acc[r]);
}

// KTVT[bh][n][k] = KTVF[bh][k][n] * 0.125 (fold 1/sqrt(64))
__global__ __launch_bounds__(256) void cast_ktv(const float* __restrict__ KTVF,
                                                u16* __restrict__ KTVT) {
    int idx = blockIdx.x * 256 + threadIdx.x;   // < 32*4096
    int bh = idx >> 12, r = idx & 4095;
    int n = r >> 6, k = r & 63;
    KTVT[idx] = f2b(KTVF[bh * 4096 + k * 64 + n] * 0.125f);
}

// ---------------- batched attn GEMM: cat[t, h*64+e'] = Q[t,:] @ KTVT[e',:] ----------------
__global__ __launch_bounds__(256) void attn_gemm(const u16* __restrict__ QKVB,
                                                 const u16* __restrict__ KTVT,
                                                 u16* __restrict__ cat) {
    __shared__ __align__(16) u16 Qs[64 * 64];
    __shared__ __align__(16) u16 Bs[64 * 64];
    int tid = threadIdx.x, wid = tid >> 6, lane = tid & 63;
    int rt = blockIdx.x, bh = blockIdx.y;
    int b = bh >> 4, h = bh & 15;
    long qbase = (long)(b * 2048 + rt * 64) * 3072 + h * 64;
#pragma unroll
    for (int i = 0; i < 2; ++i) {
        int c = i * 256 + tid;
        gload_lds16(QKVB + qbase + (c >> 3) * 3072 + (c & 7) * 8, &Qs[(i * 256 + wid * 64) * 8]);
        gload_lds16(KTVT + bh * 4096 + c * 8, &Bs[(i * 256 + wid * 64) * 8]);
    }
    __syncthreads();
    f32x4 acc[4] = {};
#pragma unroll
    for (int kk = 0; kk < 2; ++kk) {
        bf16x8 a = lds_frag(&Qs[(wid * 16 + (lane & 15)) * 64 + kk * 32 + (lane >> 4) * 8]);
#pragma unroll
        for (int n = 0; n < 4; ++n) {
            bf16x8 bb = lds_frag(&Bs[(n * 16 + (lane & 15)) * 64 + kk * 32 + (lane >> 4) * 8]);
            acc[n] = __builtin_amdgcn_mfma_f32_16x16x32_bf16(a, bb, acc[n], 0, 0, 0);
        }
    }
#pragma unroll
    for (int n = 0; n < 4; ++n)
#pragma unroll
        for (int r = 0; r < 4; ++r) {
            int row = rt * 64 + wid * 16 + (lane >> 4) * 4 + r;
            int col = h * 64 + n * 16 + (lane & 15);
            cat[(long)(b * 2048 + row) * 1024 + col] = f2b(acc[n][r]);
        }
}

// ---------------- layernorm kernels ----------------
__device__ __forceinline__ void block_reduce2(float& a, float& b) {
    __syncthreads();
#pragma unroll
    for (int off = 32; off; off >>= 1) {
        a += __shfl_down(a, off);
        b += __shfl_down(b, off);
    }
    __shared__ float sa[4], sb[4];
    int wid = threadIdx.x >> 6, lane = threadIdx.x & 63;
    if (lane == 0) { sa[wid] = a; sb[wid] = b; }
    __syncthreads();
    a = sa[0] + sa[1] + sa[2] + sa[3];
    b = sb[0] + sb[1] + sb[2] + sb[3];
}

// out1 = LN(x + (p0+p1+p2 + bp)) ; write f32 + bf16
__global__ __launch_bounds__(256) void ln1_kernel(
    const float* __restrict__ x,
    const float* __restrict__ p0, const float* __restrict__ p1, const float* __restrict__ p2,
    const float* __restrict__ bp,
    const float* __restrict__ g, const float* __restrict__ bt,
    float* __restrict__ out1f, u16* __restrict__ out1b) {
    int row = blockIdx.x, tid = threadIdx.x;
    long base = (long)row * 1024 + tid * 4;
    float4 xv = *(const float4*)&x[base];
    float4 a0 = *(const float4*)&p0[base];
    float4 a1 = *(const float4*)&p1[base];
    float4 a2 = *(const float4*)&p2[base];
    float4 bb = *(const float4*)&bp[tid * 4];
    float s[4] = { xv.x + a0.x + a1.x + a2.x + bb.x,
                   xv.y + a0.y + a1.y + a2.y + bb.y,
                   xv.z + a0.z + a1.z + a2.z + bb.z,
                   xv.w + a0.w + a1.w + a2.w + bb.w };
    float sum = s[0] + s[1] + s[2] + s[3];
    float sq = s[0] * s[0] + s[1] * s[1] + s[2] * s[2] + s[3] * s[3];
    block_reduce2(sum, sq);
    float mu = sum * (1.f / 1024.f);
    float var = sq * (1.f / 1024.f) - mu * mu;
    float rs = rsqrtf(var + 1e-5f);
    float o0 = (s[0] - mu) * rs * g[tid * 4 + 0] + bt[tid * 4 + 0];
    float o1 = (s[1] - mu) * rs * g[tid * 4 + 1] + bt[tid * 4 + 1];
    float o2 = (s[2] - mu) * rs * g[tid * 4 + 2] + bt[tid * 4 + 2];
    float o3 = (s[3] - mu) * rs * g[tid * 4 + 3] + bt[tid * 4 + 3];
    float4 of; of.x = o0; of.y = o1; of.z = o2; of.w = o3;
    u16x4 ob = (u16x4){ f2b(o0), f2b(o1), f2b(o2), f2b(o3) };
    *(float4*)&out1f[base] = of;
    *(u16x4*)&out1b[base] = ob;
}

// ff = (q0+q1+q2+q3)+b2 (bf16 partials); ffo = LN(out1+ff); out2 = LN(out1+ffo)
__global__ __launch_bounds__(256) void lnf_kernel(
    const float* __restrict__ out1f,
    const u16* __restrict__ q0, const u16* __restrict__ q1,
    const u16* __restrict__ q2, const u16* __restrict__ q3,
    const float* __restrict__ b2,
    const float* __restrict__ lnfg, const float* __restrict__ lnfb,
    const float* __restrict__ ln2g, const float* __restrict__ ln2b,
    float* __restrict__ out2) {
    int row = blockIdx.x, tid = threadIdx.x;
    long base = (long)row * 1024 + tid * 4;
    float4 o1 = *(const float4*)&out1f[base];
    u16x4 a0 = *(const u16x4*)&q0[base];
    u16x4 a1 = *(const u16x4*)&q1[base];
    u16x4 a2 = *(const u16x4*)&q2[base];
    u16x4 a3 = *(const u16x4*)&q3[base];
    float4 bb = *(const float4*)&b2[tid * 4];
    float o1a[4] = { o1.x, o1.y, o1.z, o1.w };
    float bba[4] = { bb.x, bb.y, bb.z, bb.w };
    float s1[4];
#pragma unroll
    for (int r = 0; r < 4; ++r)
        s1[r] = o1a[r] + b2f(a0[r]) + b2f(a1[r]) + b2f(a2[r]) + b2f(a3[r]) + bba[r];
    float sum = s1[0] + s1[1] + s1[2] + s1[3];
    float sq = s1[0] * s1[0] + s1[1] * s1[1] + s1[2] * s1[2] + s1[3] * s1[3];
    block_reduce2(sum, sq);
    float mu = sum * (1.f / 1024.f);
    float rs = rsqrtf(sq * (1.f / 1024.f) - mu * mu + 1e-5f);
    float s2[4];
#pragma unroll
    for (int r = 0; r < 4; ++r) {
        float ffo = (s1[r] - mu) * rs * lnfg[tid * 4 + r] + lnfb[tid * 4 + r];
        s2[r] = o1a[r] + ffo;
    }
    float sum2 = s2[0] + s2[1] + s2[2] + s2[3];
    float sq2 = s2[0] * s2[0] + s2[1] * s2[1] + s2[2] * s2[2] + s2[3] * s2[3];
    block_reduce2(sum2, sq2);
    float mu2 = sum2 * (1.f / 1024.f);
    float rs2 = rsqrtf(sq2 * (1.f / 1024.f) - mu2 * mu2 + 1e-5f);
    float4 o;
    o.x = (s2[0] - mu2) * rs2 * ln2g[tid * 4 + 0] + ln2b[tid * 4 + 0];
    o.y = (s2[1] - mu2) * rs2 * ln2g[tid * 4 + 1] + ln2b[tid * 4 + 1];
    o.z = (s2[2] - mu2) * rs2 * ln2g[tid * 4 + 2] + ln2b[tid * 4 + 2];
    o.w = (s2[3] - mu2) * rs2 * ln2g[tid * 4 + 3] + ln2b[tid * 4 + 3];
    *(float4*)&out2[base] = o;
}

// ---------------- launcher ----------------
extern "C" void kernel_launch(void* const* d_in, const int* in_sizes, int n_in,
                              void* d_out, int out_size, void* d_ws, size_t ws_size,
                              hipStream_t stream) {
    const float* x    = (const float*)d_in[0];
    const float* wq   = (const float*)d_in[1];
    const float* bq   = (const float*)d_in[2];
    const float* wk   = (const float*)d_in[3];
    const float* bk   = (const float*)d_in[4];
    const float* wv   = (const float*)d_in[5];
    const float* bv   = (const float*)d_in[6];
    const float* wp   = (const float*)d_in[7];
    const float* bp   = (const float*)d_in[8];
    const float* w1   = (const float*)d_in[9];
    const float* b1   = (const float*)d_in[10];
    const float* w2   = (const float*)d_in[11];
    const float* b2   = (const float*)d_in[12];
    const float* ln1g = (const float*)d_in[13];
    const float* ln1b = (const float*)d_in[14];
    const float* lnfg = (const float*)d_in[15];
    const float* lnfb = (const float*)d_in[16];
    const float* ln2g = (const float*)d_in[17];
    const float* ln2b = (const float*)d_in[18];

    float* out2 = (float*)d_out;
    float* kv   = (float*)d_out + 4194304;   // Kc then Vc

    // workspace layout (bytes). Liveness:
    char* ws = (char*)d_ws;
    u16*   XB     = (u16*)  (ws + 0);          // 8 MB  (dead after G1); reused: CAT (dead after G3), G5 Q0
    u16*   CAT    = XB;
    u16*   WQKVT  = (u16*)  (ws + 8388608);    // 6 MB  (dead after G1)
    float* BQKV   = (float*)(ws + 14680064);   // 12 KB (dead after G1)
    u16*   WPT    = (u16*)  (ws + 14692352);   // 2 MB  (dead after G3)
    u16*   W1T    = (u16*)  (ws + 16789504);   // 8 MB  (dead after G4)
    u16*   W2T    = (u16*)  (ws + 25178112);   // 8 MB  (live through G5)
    float* KTVF   = (float*)(ws + 33566720);   // 512 KB
    u16*   KTVT   = (u16*)  (ws + 34091008);   // 256 KB
    u16*   QKVB   = (u16*)  (ws + 34353152);   // 24 MB (dead after attn); reused: OUT1B, then G5 Q1..Q3
    u16*   OUT1B  = QKVB;
    float* G3P0   = (float*)(ws + 59518976);   // 16 MB (dead after ln1)
    float* OUT1F  = (float*)(ws + 76296192);   // 16 MB (live to lnf)
    float* G3P1   = (float*)(ws + 93073408);   // 16 MB (dead after ln1); then H1
    float* G3P2   = (float*)(ws + 109850624);  // 16 MB (dead after ln1); then H1
    u16*   H1     = (u16*)  (ws + 93073408);   // 32 MB (live through G5)
    u16*   Q5_0   = (u16*)  (ws + 0);          // 8 MB bf16 partial (over XB/CAT)
    u16*   Q5_1   = (u16*)  (ws + 34353152);   // 8 MB (over OUT1B, dead after G4)
    u16*   Q5_2   = (u16*)  (ws + 42741760);   // 8 MB
    u16*   Q5_3   = (u16*)  (ws + 51130368);   // 8 MB (ends exactly at 59518976)
    (void)ws_size; (void)in_sizes; (void)n_in; (void)out_size;

    hipMemsetAsync(KTVF, 0, 32 * 4096 * 4, stream);
    cast_x_kernel<<<4096, 256, 0, stream>>>(x, XB);
    prep_wqkv_kernel<<<12288, 256, 0, stream>>>(wq, wk, wv, bq, bk, bv, WQKVT, BQKV);
    transpose_cast<<<dim3(32, 32), 256, 0, stream>>>(wp, WPT, 1024, 1024);
    transpose_cast<<<dim3(128, 32), 256, 0, stream>>>(w1, W1T, 1024, 4096);
    transpose_cast<<<dim3(32, 128), 256, 0, stream>>>(w2, W2T, 4096, 1024);

    // G1: QKV = X @ Wqkv + b  (bf16 out + Kc/Vc f32 side-out)
    gemm256<1><<<192, 512, 0, stream>>>(XB, WQKVT, BQKV, QKVB, kv,
                                        nullptr, nullptr, nullptr, nullptr,
                                        4096, 3072, 1024, 1024, 1024, 3072, 0);
    ktv_partial<<<dim3(8, 32), 256, 0, stream>>>(QKVB, KTVF);
    cast_ktv<<<512, 256, 0, stream>>>(KTVF, KTVT);
    attn_gemm<<<dim3(32, 32), 256, 0, stream>>>(QKVB, KTVT, CAT);

    // G3: out = cat @ wp (split-K x3, f32 partials; bias folded into ln1)
    gemm128<4><<<768, 256, 0, stream>>>(CAT, WPT, nullptr, nullptr, G3P0, nullptr, G3P1, G3P2,
                                        4096, 1024, 1024, 1024, 1024, 1024, 352);
    ln1_kernel<<<4096, 256, 0, stream>>>(x, G3P0, G3P1, G3P2, bp, ln1g, ln1b, OUT1F, OUT1B);

    // G4: h1 = relu(out1 @ w1 + b1) (bf16)
    gemm256<2><<<256, 512, 0, stream>>>(OUT1B, W1T, b1, H1, nullptr,
                                        nullptr, nullptr, nullptr, nullptr,
                                        4096, 4096, 1024, 1024, 1024, 4096, 0);
    // G5: ff = h1 @ w2 (split-K x4, bf16 partials; bias folded into lnf)
    gemm256<4><<<256, 512, 0, stream>>>(H1, W2T, nullptr, nullptr, nullptr,
                                        Q5_0, Q5_1, Q5_2, Q5_3,
                                        4096, 1024, 4096, 4096, 4096, 1024, 1024);
    lnf_kernel<<<4096, 256, 0, stream>>>(OUT1F, Q5_0, Q5_1, Q5_2, Q5_3, b2,
                                         lnfg, lnfb, ln2g, ln2b, out2);
}

// Round 4
// 235.067 us; speedup vs baseline: 1.3149x; 1.0151x over previous
//
#include <hip/hip_runtime.h>

typedef unsigned short u16;
typedef __attribute__((ext_vector_type(4))) float f32x4;
typedef __attribute__((ext_vector_type(8))) __bf16 bf16x8;
typedef __attribute__((ext_vector_type(8))) unsigned short u16x8;
typedef __attribute__((ext_vector_type(4))) unsigned short u16x4;

// ---------- scalar bf16 helpers ----------
__device__ __forceinline__ u16 f2b(float f) {
    unsigned int u = __builtin_bit_cast(unsigned int, f);
    u = (u + 0x7FFFu + ((u >> 16) & 1u)) >> 16;
    return (u16)u;
}
__device__ __forceinline__ float b2f(u16 h) {
    unsigned int u = ((unsigned int)h) << 16;
    return __builtin_bit_cast(float, u);
}

// async global->LDS, 16B per lane; LDS dest is wave-uniform base (+lane*16 by HW)
__device__ __forceinline__ void gload_lds16(const u16* g, u16* l) {
    __builtin_amdgcn_global_load_lds(
        (const __attribute__((address_space(1))) void*)g,
        (__attribute__((address_space(3))) void*)l,
        16, 0, 0);
}

__device__ __forceinline__ bf16x8 lds_frag(const u16* p) {
    u16x8 t = *(const u16x8*)p;
    return __builtin_bit_cast(bf16x8, t);
}

#define FENCE asm volatile("" ::: "memory")
#define BARRIER do { FENCE; __builtin_amdgcn_s_barrier(); FENCE; \
                     __builtin_amdgcn_sched_barrier(0); } while (0)
#define LGKM0 do { asm volatile("s_waitcnt lgkmcnt(0)" ::: "memory"); \
                   __builtin_amdgcn_sched_barrier(0); } while (0)
#define WAIT_VM8 do { asm volatile("s_waitcnt vmcnt(8)" ::: "memory"); \
                      __builtin_amdgcn_sched_barrier(0); } while (0)
#define WAIT_VM4 do { asm volatile("s_waitcnt vmcnt(4)" ::: "memory"); \
                      __builtin_amdgcn_sched_barrier(0); } while (0)
#define WAIT_VM0 do { asm volatile("s_waitcnt vmcnt(0)" ::: "memory"); \
                      __builtin_amdgcn_sched_barrier(0); } while (0)

// ---------------- prep kernels ----------------
__global__ __launch_bounds__(256) void cast_x_kernel(const float* __restrict__ in,
                                                     u16* __restrict__ out) {
    int i = (blockIdx.x * 256 + threadIdx.x) * 4;
    float4 v = *(const float4*)&in[i];
    u16x4 o = { f2b(v.x), f2b(v.y), f2b(v.z), f2b(v.w) };
    *(u16x4*)&out[i] = o;
}

// WqkvT[n][d] = w_sel[h][d][e], n = sel*1024 + h*64 + e ; also bias vec [3072]
__global__ __launch_bounds__(256) void prep_wqkv_kernel(
    const float* __restrict__ wq, const float* __restrict__ wk, const float* __restrict__ wv,
    const float* __restrict__ bq, const float* __restrict__ bk, const float* __restrict__ bv,
    u16* __restrict__ WT, float* __restrict__ BI) {
    int idx = blockIdx.x * 256 + threadIdx.x;     // < 3072*1024
    int n = idx >> 10, d = idx & 1023;
    int sel = n >> 10, hh = (n & 1023) >> 6, e = n & 63;
    const float* w = (sel == 0) ? wq : (sel == 1) ? wk : wv;
    WT[idx] = f2b(w[(hh * 1024 + d) * 64 + e]);
    if (idx < 3072) {
        const float* bb = (idx < 1024) ? bq : (idx < 2048) ? bk : bv;
        BI[idx] = bb[((idx & 1023) >> 6) * 64 + (idx & 63)];
    }
}

// out[c][r] = (bf16) in[r][c]   (in: [R][C] f32)
__global__ __launch_bounds__(256) void transpose_cast(const float* __restrict__ in,
                                                      u16* __restrict__ out, int R, int C) {
    __shared__ float tile[32][33];
    int tx = threadIdx.x & 31, ty = threadIdx.x >> 5;   // 32 x 8
    int r0 = blockIdx.y * 32, c0 = blockIdx.x * 32;
#pragma unroll
    for (int i = 0; i < 32; i += 8)
        tile[ty + i][tx] = in[(long)(r0 + ty + i) * C + c0 + tx];
    __syncthreads();
#pragma unroll
    for (int i = 0; i < 32; i += 8)
        out[(long)(c0 + ty + i) * R + r0 + tx] = f2b(tile[tx][ty + i]);
}

// ---------------- 256x256 8-wave BK=64 GEMM, 8-phase counted-vmcnt pipeline -----
// C[M,N] = A[M,K] @ BT[N,K]^T.
// MODE 1: +bias, bf16 out to Cb, f32 side-write cols>=1024 into KV (G1).
// MODE 2: +bias, relu, bf16 out to Cb (G4).
// MODE 4: split-K bf16 partials (no bias) to Q0..Q3 by sk (G3, G5). nt must be EVEN.
// LDS per slot: [256 rows][64 k] bf16; byte-swizzle col^=(row&7)<<4, applied on the
// inverse-swizzled GLOBAL source for staging (rule #21) and on ds_read addresses.
// Iteration I computes K-tile 2I from slot0 (phases 1-4) and 2I+1 from slot1 (5-8).
// Stage events (4 gloads each): A1B1(t0+1)->S1 @P1 (I>0); A0B0(t0+2)->S0 @P4;
// A1B1(t0+2)->S0 @P5; A0B0(t0+3)->S1 @P8. vmcnt(4) at P4/P8 retires exactly the
// tile needed next; 4 loads stay in flight (never drain mid-loop).
#define PHASE(Sa, Sb, mh, kh, LOADB, STAGE_STMT, WAIT_STMT) do {              \
    if (LOADB) {                                                              \
        _Pragma("unroll") for (int n = 0; n < 4; ++n)                         \
            bfr[n] = lds_frag(&(Sb)[((brow0 + (n << 4)) << 6) +               \
                                    (eoff ^ ((kh) * 32))]);                   \
    }                                                                         \
    _Pragma("unroll") for (int m4 = 0; m4 < 4; ++m4)                          \
        af[m4] = lds_frag(&(Sa)[((arow0 + (((mh) * 4 + m4) << 4)) << 6) +     \
                                (eoff ^ ((kh) * 32))]);                       \
    STAGE_STMT;                                                               \
    BARRIER;                                                                  \
    LGKM0;                                                                    \
    __builtin_amdgcn_s_setprio(1);                                            \
    _Pragma("unroll") for (int m4 = 0; m4 < 4; ++m4)                          \
        _Pragma("unroll") for (int n = 0; n < 4; ++n)                         \
            acc[(mh) * 4 + m4][n] = __builtin_amdgcn_mfma_f32_16x16x32_bf16(  \
                af[m4], bfr[n], acc[(mh) * 4 + m4][n], 0, 0, 0);              \
    __builtin_amdgcn_s_setprio(0);                                            \
    WAIT_STMT;                                                                \
    BARRIER;                                                                  \
} while (0)

template <int MODE>
__global__ __launch_bounds__(512, 2) void gemm256(
    const u16* __restrict__ A, const u16* __restrict__ BT, const float* __restrict__ bias,
    u16* __restrict__ Cb, float* __restrict__ KV,
    u16* __restrict__ Q0, u16* __restrict__ Q1, u16* __restrict__ Q2, u16* __restrict__ Q3,
    int M, int N, int K, int lda, int ldb, int ldc, int kchunk) {
    __shared__ __align__(16) u16 As[2][16384];
    __shared__ __align__(16) u16 Bs[2][16384];
    const int tid = threadIdx.x;
    const int lane = tid & 63;
    const int wid = tid >> 6;
    const int wr = wid >> 2, wc = wid & 3;
    const int ntile = N >> 8;
    int bid = blockIdx.x;
    int kb = 0, ksz = K;
    u16* Pout = Q0;
    if (MODE == 4) {
        int tiles = (M >> 8) * ntile;
        int sk = bid / tiles; bid -= sk * tiles;
        kb = sk * kchunk;
        int rem = K - kb; ksz = rem < kchunk ? rem : kchunk;
        Pout = (sk == 0) ? Q0 : (sk == 1) ? Q1 : (sk == 2) ? Q2 : Q3;
    }
    const int bi = bid / ntile, bj = bid % ntile;
    const int brow = bi << 8, bcol = bj << 8;
    const int nt = ksz >> 6;     // BK=64 tiles; even by construction
    const int niter = nt >> 1;

    // ---- staging addressing (inverse-swizzled global source, linear LDS dest)
    const int srow = tid >> 3;                        // 0..63 (+j*64)
    const int scol = ((tid & 7) ^ (srow & 7)) << 3;   // element offset in row
    const u16* ag = A + (long)(brow + srow) * lda + kb + scol;
    const u16* bg = BT + (long)(bcol + srow) * ldb + kb + scol;
    const long a64 = (long)lda << 6, b64 = (long)ldb << 6;
    const int sdst = tid << 3;                        // u16 elems (+j*4096)

    // stage one half-pair (A-half + B-half = 4 gloads): jb=0 -> rows 0-127, jb=2 -> 128-255
    auto STG = [&](u16* lA, u16* lB, int t, int jb) {
#pragma unroll
        for (int j = 0; j < 2; ++j) {
            gload_lds16(ag + ((long)t << 6) + (jb + j) * a64, &lA[(jb + j) * 4096 + sdst]);
            gload_lds16(bg + ((long)t << 6) + (jb + j) * b64, &lB[(jb + j) * 4096 + sdst]);
        }
    };

    f32x4 acc[8][4] = {};

    // ---- fragment read addressing (swizzled)
    const int ln15 = lane & 15;
    const int eoff = (((lane >> 4) << 3) ^ ((lane & 7) << 3));
    const int arow0 = (wr << 7) + ln15;
    const int brow0 = (wc << 6) + ln15;

    // ---- prologue: stage tile0 (slot0) + tile1 (slot1); wait tile0, keep tile1 in flight
    STG(As[0], Bs[0], 0, 0); STG(As[0], Bs[0], 0, 2);
    if (nt > 1) { STG(As[1], Bs[1], 1, 0); STG(As[1], Bs[1], 1, 2); WAIT_VM8; }
    else WAIT_VM0;
    BARRIER;

    for (int I = 0; I < niter; ++I) {
        const int t0 = 2 * I;
        const bool hn0 = (t0 + 2 < nt);
        const bool hn1 = (t0 + 3 < nt);
        const bool notlast = (I + 1 < niter);
        bf16x8 af[4], bfr[4];
        // ---- tile t0 from slot0
        PHASE(As[0], Bs[0], 0, 0, true,
              { if (I > 0) STG(As[1], Bs[1], t0 + 1, 2); }, {});
        PHASE(As[0], Bs[0], 1, 0, false, {}, {});
        PHASE(As[0], Bs[0], 0, 1, true, {}, {});
        PHASE(As[0], Bs[0], 1, 1, false,
              { if (hn0) STG(As[0], Bs[0], t0 + 2, 0); },
              { if (hn0) WAIT_VM4; else WAIT_VM0; });
        // ---- tile t0+1 from slot1
        PHASE(As[1], Bs[1], 0, 0, true,
              { if (hn0) STG(As[0], Bs[0], t0 + 2, 2); }, {});
        PHASE(As[1], Bs[1], 1, 0, false, {}, {});
        PHASE(As[1], Bs[1], 0, 1, true, {}, {});
        PHASE(As[1], Bs[1], 1, 1, false,
              { if (hn1) STG(As[1], Bs[1], t0 + 3, 0); },
              { if (notlast) { if (hn1) WAIT_VM4; else WAIT_VM0; } });
    }

    // ---- epilogue
#pragma unroll
    for (int m = 0; m < 8; ++m) {
        int row = brow + (wr << 7) + (m << 4) + ((lane >> 4) << 2);
#pragma unroll
        for (int n = 0; n < 4; ++n) {
            int col = bcol + (wc << 6) + (n << 4) + ln15;
            float bv = (MODE == 4) ? 0.f : bias[col];
#pragma unroll
            for (int r = 0; r < 4; ++r) {
                float v = acc[m][n][r] + bv;
                long off = (long)(row + r) * ldc + col;
                if (MODE == 2) { v = v > 0.f ? v : 0.f; Cb[off] = f2b(v); }
                if (MODE == 1) {
                    Cb[off] = f2b(v);
                    if (col >= 1024) {
                        int c = col - 1024;
                        KV[(long)(c >> 10) * 4194304 + (long)(row + r) * 1024 + (c & 1023)] = v;
                    }
                }
                if (MODE == 4) Pout[off] = f2b(v);
            }
        }
    }
}

// ---------------- K^T V partial sums (t-chunked, f32 atomics) ----------------
__global__ __launch_bounds__(256) void ktv_partial(const u16* __restrict__ QKVB,
                                                   float* __restrict__ KTVF) {
    __shared__ __align__(16) u16 Ks[64 * 64];
    __shared__ __align__(16) u16 Vs[64 * 64];
    int tid = threadIdx.x;
    int tc = blockIdx.x, bh = blockIdx.y;
    int b = bh >> 4, h = bh & 15;
    int j = tid & 63, i0 = (tid >> 6) * 16;
    float acc[16] = {};
    for (int st = 0; st < 4; ++st) {
        int t0 = tc * 256 + st * 64;
        __syncthreads();
#pragma unroll
        for (int i = 0; i < 2; ++i) {
            int c = i * 256 + tid;
            long base = (long)(b * 2048 + t0 + (c >> 3)) * 3072 + h * 64 + (c & 7) * 8;
            *(u16x8*)&Ks[c * 8] = *(const u16x8*)&QKVB[base + 1024];
            *(u16x8*)&Vs[c * 8] = *(const u16x8*)&QKVB[base + 2048];
        }
        __syncthreads();
        for (int tt = 0; tt < 64; ++tt) {
            float vj = b2f(Vs[tt * 64 + j]);
            u16x8 k0 = *(const u16x8*)&Ks[tt * 64 + i0];
            u16x8 k1 = *(const u16x8*)&Ks[tt * 64 + i0 + 8];
#pragma unroll
            for (int r = 0; r < 8; ++r) acc[r] += b2f(k0[r]) * vj;
#pragma unroll
            for (int r = 0; r < 8; ++r) acc[r + 8] += b2f(k1[r]) * vj;
        }
    }
#pragma unroll
    for (int r = 0; r < 16; ++r)
        atomicAdd(&KTVF[bh * 4096 + (i0 + r) * 64 + j], acc[r]);
}

// KTVT[bh][n][k] = KTVF[bh][k][n] * 0.125 (fold 1/sqrt(64))
__global__ __launch_bounds__(256) void cast_ktv(const float* __restrict__ KTVF,
                                                u16* __restrict__ KTVT) {
    int idx = blockIdx.x * 256 + threadIdx.x;   // < 32*4096
    int bh = idx >> 12, r = idx & 4095;
    int n = r >> 6, k = r & 63;
    KTVT[idx] = f2b(KTVF[bh * 4096 + k * 64 + n] * 0.125f);
}

// ---------------- batched attn GEMM: cat[t, h*64+e'] = Q[t,:] @ KTVT[e',:] -------
__global__ __launch_bounds__(256) void attn_gemm(const u16* __restrict__ QKVB,
                                                 const u16* __restrict__ KTVT,
                                                 u16* __restrict__ cat) {
    __shared__ __align__(16) u16 Qs[64 * 64];
    __shared__ __align__(16) u16 Bs[64 * 64];
    int tid = threadIdx.x, wid = tid >> 6, lane = tid & 63;
    int rt = blockIdx.x, bh = blockIdx.y;
    int b = bh >> 4, h = bh & 15;
    long qbase = (long)(b * 2048 + rt * 64) * 3072 + h * 64;
#pragma unroll
    for (int i = 0; i < 2; ++i) {
        int c = i * 256 + tid;
        gload_lds16(QKVB + qbase + (c >> 3) * 3072 + (c & 7) * 8, &Qs[(i * 256 + wid * 64) * 8]);
        gload_lds16(KTVT + bh * 4096 + c * 8, &Bs[(i * 256 + wid * 64) * 8]);
    }
    __syncthreads();
    f32x4 acc[4] = {};
#pragma unroll
    for (int kk = 0; kk < 2; ++kk) {
        bf16x8 a = lds_frag(&Qs[(wid * 16 + (lane & 15)) * 64 + kk * 32 + (lane >> 4) * 8]);
#pragma unroll
        for (int n = 0; n < 4; ++n) {
            bf16x8 bb = lds_frag(&Bs[(n * 16 + (lane & 15)) * 64 + kk * 32 + (lane >> 4) * 8]);
            acc[n] = __builtin_amdgcn_mfma_f32_16x16x32_bf16(a, bb, acc[n], 0, 0, 0);
        }
    }
#pragma unroll
    for (int n = 0; n < 4; ++n)
#pragma unroll
        for (int r = 0; r < 4; ++r) {
            int row = rt * 64 + wid * 16 + (lane >> 4) * 4 + r;
            int col = h * 64 + n * 16 + (lane & 15);
            cat[(long)(b * 2048 + row) * 1024 + col] = f2b(acc[n][r]);
        }
}

// ---------------- layernorm kernels ----------------
__device__ __forceinline__ void block_reduce2(float& a, float& b) {
    __syncthreads();
#pragma unroll
    for (int off = 32; off; off >>= 1) {
        a += __shfl_down(a, off);
        b += __shfl_down(b, off);
    }
    __shared__ float sa[4], sb[4];
    int wid = threadIdx.x >> 6, lane = threadIdx.x & 63;
    if (lane == 0) { sa[wid] = a; sb[wid] = b; }
    __syncthreads();
    a = sa[0] + sa[1] + sa[2] + sa[3];
    b = sb[0] + sb[1] + sb[2] + sb[3];
}

// out1 = LN(x + (q0+q1+q2+q3 + bp)) ; write f32 + bf16  (q* = bf16 partials)
__global__ __launch_bounds__(256) void ln1_kernel(
    const float* __restrict__ x,
    const u16* __restrict__ q0, const u16* __restrict__ q1,
    const u16* __restrict__ q2, const u16* __restrict__ q3,
    const float* __restrict__ bp,
    const float* __restrict__ g, const float* __restrict__ bt,
    float* __restrict__ out1f, u16* __restrict__ out1b) {
    int row = blockIdx.x, tid = threadIdx.x;
    long base = (long)row * 1024 + tid * 4;
    float4 xv = *(const float4*)&x[base];
    u16x4 a0 = *(const u16x4*)&q0[base];
    u16x4 a1 = *(const u16x4*)&q1[base];
    u16x4 a2 = *(const u16x4*)&q2[base];
    u16x4 a3 = *(const u16x4*)&q3[base];
    float4 bb = *(const float4*)&bp[tid * 4];
    float xa[4] = { xv.x, xv.y, xv.z, xv.w };
    float bba[4] = { bb.x, bb.y, bb.z, bb.w };
    float s[4];
#pragma unroll
    for (int r = 0; r < 4; ++r)
        s[r] = xa[r] + b2f(a0[r]) + b2f(a1[r]) + b2f(a2[r]) + b2f(a3[r]) + bba[r];
    float sum = s[0] + s[1] + s[2] + s[3];
    float sq = s[0] * s[0] + s[1] * s[1] + s[2] * s[2] + s[3] * s[3];
    block_reduce2(sum, sq);
    float mu = sum * (1.f / 1024.f);
    float var = sq * (1.f / 1024.f) - mu * mu;
    float rs = rsqrtf(var + 1e-5f);
    float o0 = (s[0] - mu) * rs * g[tid * 4 + 0] + bt[tid * 4 + 0];
    float o1 = (s[1] - mu) * rs * g[tid * 4 + 1] + bt[tid * 4 + 1];
    float o2 = (s[2] - mu) * rs * g[tid * 4 + 2] + bt[tid * 4 + 2];
    float o3 = (s[3] - mu) * rs * g[tid * 4 + 3] + bt[tid * 4 + 3];
    float4 of; of.x = o0; of.y = o1; of.z = o2; of.w = o3;
    u16x4 ob = (u16x4){ f2b(o0), f2b(o1), f2b(o2), f2b(o3) };
    *(float4*)&out1f[base] = of;
    *(u16x4*)&out1b[base] = ob;
}

// ff = (q0+q1+q2+q3)+b2 (bf16 partials); ffo = LN(out1+ff); out2 = LN(out1+ffo)
__global__ __launch_bounds__(256) void lnf_kernel(
    const float* __restrict__ out1f,
    const u16* __restrict__ q0, const u16* __restrict__ q1,
    const u16* __restrict__ q2, const u16* __restrict__ q3,
    const float* __restrict__ b2,
    const float* __restrict__ lnfg, const float* __restrict__ lnfb,
    const float* __restrict__ ln2g, const float* __restrict__ ln2b,
    float* __restrict__ out2) {
    int row = blockIdx.x, tid = threadIdx.x;
    long base = (long)row * 1024 + tid * 4;
    float4 o1 = *(const float4*)&out1f[base];
    u16x4 a0 = *(const u16x4*)&q0[base];
    u16x4 a1 = *(const u16x4*)&q1[base];
    u16x4 a2 = *(const u16x4*)&q2[base];
    u16x4 a3 = *(const u16x4*)&q3[base];
    float4 bb = *(const float4*)&b2[tid * 4];
    float o1a[4] = { o1.x, o1.y, o1.z, o1.w };
    float bba[4] = { bb.x, bb.y, bb.z, bb.w };
    float s1[4];
#pragma unroll
    for (int r = 0; r < 4; ++r)
        s1[r] = o1a[r] + b2f(a0[r]) + b2f(a1[r]) + b2f(a2[r]) + b2f(a3[r]) + bba[r];
    float sum = s1[0] + s1[1] + s1[2] + s1[3];
    float sq = s1[0] * s1[0] + s1[1] * s1[1] + s1[2] * s1[2] + s1[3] * s1[3];
    block_reduce2(sum, sq);
    float mu = sum * (1.f / 1024.f);
    float rs = rsqrtf(sq * (1.f / 1024.f) - mu * mu + 1e-5f);
    float s2[4];
#pragma unroll
    for (int r = 0; r < 4; ++r) {
        float ffo = (s1[r] - mu) * rs * lnfg[tid * 4 + r] + lnfb[tid * 4 + r];
        s2[r] = o1a[r] + ffo;
    }
    float sum2 = s2[0] + s2[1] + s2[2] + s2[3];
    float sq2 = s2[0] * s2[0] + s2[1] * s2[1] + s2[2] * s2[2] + s2[3] * s2[3];
    block_reduce2(sum2, sq2);
    float mu2 = sum2 * (1.f / 1024.f);
    float rs2 = rsqrtf(sq2 * (1.f / 1024.f) - mu2 * mu2 + 1e-5f);
    float4 o;
    o.x = (s2[0] - mu2) * rs2 * ln2g[tid * 4 + 0] + ln2b[tid * 4 + 0];
    o.y = (s2[1] - mu2) * rs2 * ln2g[tid * 4 + 1] + ln2b[tid * 4 + 1];
    o.z = (s2[2] - mu2) * rs2 * ln2g[tid * 4 + 2] + ln2b[tid * 4 + 2];
    o.w = (s2[3] - mu2) * rs2 * ln2g[tid * 4 + 3] + ln2b[tid * 4 + 3];
    *(float4*)&out2[base] = o;
}

// ---------------- launcher ----------------
extern "C" void kernel_launch(void* const* d_in, const int* in_sizes, int n_in,
                              void* d_out, int out_size, void* d_ws, size_t ws_size,
                              hipStream_t stream) {
    const float* x    = (const float*)d_in[0];
    const float* wq   = (const float*)d_in[1];
    const float* bq   = (const float*)d_in[2];
    const float* wk   = (const float*)d_in[3];
    const float* bk   = (const float*)d_in[4];
    const float* wv   = (const float*)d_in[5];
    const float* bv   = (const float*)d_in[6];
    const float* wp   = (const float*)d_in[7];
    const float* bp   = (const float*)d_in[8];
    const float* w1   = (const float*)d_in[9];
    const float* b1   = (const float*)d_in[10];
    const float* w2   = (const float*)d_in[11];
    const float* b2   = (const float*)d_in[12];
    const float* ln1g = (const float*)d_in[13];
    const float* ln1b = (const float*)d_in[14];
    const float* lnfg = (const float*)d_in[15];
    const float* lnfb = (const float*)d_in[16];
    const float* ln2g = (const float*)d_in[17];
    const float* ln2b = (const float*)d_in[18];

    float* out2 = (float*)d_out;
    float* kv   = (float*)d_out + 4194304;   // Kc then Vc

    // workspace layout (bytes). Liveness:
    char* ws = (char*)d_ws;
    u16*   XB     = (u16*)  (ws + 0);          // 8 MB (dead after G1); CAT (dead after G3); Q5_0
    u16*   CAT    = XB;
    u16*   WQKVT  = (u16*)  (ws + 8388608);    // 6.3 MB (dead after G1)
    float* BQKV   = (float*)(ws + 14680064);   // 12 KB (dead after G1)
    u16*   WPT    = (u16*)  (ws + 14692352);   // 2 MB (dead after G3)
    u16*   W1T    = (u16*)  (ws + 16789504);   // 8 MB (dead after G4)
    u16*   W2T    = (u16*)  (ws + 25178112);   // 8 MB (live through G5)
    float* KTVF   = (float*)(ws + 33566720);   // 512 KB
    u16*   KTVT   = (u16*)  (ws + 34091008);   // 256 KB
    u16*   QKVB   = (u16*)  (ws + 34353152);   // 24 MB (dead after attn); OUT1B (dead after G4)
    u16*   OUT1B  = QKVB;
    u16*   Q3_2   = (u16*)  (ws + 42741760);   // 8 MB (inside dead QKVB tail; dead after ln1)
    u16*   Q3_3   = (u16*)  (ws + 51130368);   // 8 MB (dead after ln1); then Q5_2/Q5_3
    u16*   Q3_0   = (u16*)  (ws + 59518976);   // 8 MB (dead after ln1)
    u16*   Q3_1   = (u16*)  (ws + 67907584);   // 8 MB (dead after ln1)
    float* OUT1F  = (float*)(ws + 76296192);   // 16 MB (live to lnf)
    u16*   H1     = (u16*)  (ws + 93073408);   // 32 MB (live through G5)
    u16*   Q5_0   = (u16*)  (ws + 0);          // 8 MB (over XB/CAT)
    u16*   Q5_1   = (u16*)  (ws + 34353152);   // 8 MB (over OUT1B, dead after G4)
    u16*   Q5_2   = (u16*)  (ws + 42741760);   // 8 MB
    u16*   Q5_3   = (u16*)  (ws + 51130368);   // 8 MB
    (void)ws_size; (void)in_sizes; (void)n_in; (void)out_size;

    hipMemsetAsync(KTVF, 0, 32 * 4096 * 4, stream);
    cast_x_kernel<<<4096, 256, 0, stream>>>(x, XB);
    prep_wqkv_kernel<<<12288, 256, 0, stream>>>(wq, wk, wv, bq, bk, bv, WQKVT, BQKV);
    transpose_cast<<<dim3(32, 32), 256, 0, stream>>>(wp, WPT, 1024, 1024);
    transpose_cast<<<dim3(128, 32), 256, 0, stream>>>(w1, W1T, 1024, 4096);
    transpose_cast<<<dim3(32, 128), 256, 0, stream>>>(w2, W2T, 4096, 1024);

    // G1: QKV = X @ Wqkv + b  (bf16 out + Kc/Vc f32 side-out)
    gemm256<1><<<192, 512, 0, stream>>>(XB, WQKVT, BQKV, QKVB, kv,
                                        nullptr, nullptr, nullptr, nullptr,
                                        4096, 3072, 1024, 1024, 1024, 3072, 0);
    ktv_partial<<<dim3(8, 32), 256, 0, stream>>>(QKVB, KTVF);
    cast_ktv<<<512, 256, 0, stream>>>(KTVF, KTVT);
    attn_gemm<<<dim3(32, 32), 256, 0, stream>>>(QKVB, KTVT, CAT);

    // G3: out = cat @ wp (split-K x4, bf16 partials; bias folded into ln1)
    gemm256<4><<<256, 512, 0, stream>>>(CAT, WPT, nullptr, nullptr, nullptr,
                                        Q3_0, Q3_1, Q3_2, Q3_3,
                                        4096, 1024, 1024, 1024, 1024, 1024, 256);
    ln1_kernel<<<4096, 256, 0, stream>>>(x, Q3_0, Q3_1, Q3_2, Q3_3, bp,
                                         ln1g, ln1b, OUT1F, OUT1B);

    // G4: h1 = relu(out1 @ w1 + b1) (bf16)
    gemm256<2><<<256, 512, 0, stream>>>(OUT1B, W1T, b1, H1, nullptr,
                                        nullptr, nullptr, nullptr, nullptr,
                                        4096, 4096, 1024, 1024, 1024, 4096, 0);
    // G5: ff = h1 @ w2 (split-K x4, bf16 partials; bias folded into lnf)
    gemm256<4><<<256, 512, 0, stream>>>(H1, W2T, nullptr, nullptr, nullptr,
                                        Q5_0, Q5_1, Q5_2, Q5_3,
                                        4096, 1024, 4096, 4096, 4096, 1024, 1024);
    lnf_kernel<<<4096, 256, 0, stream>>>(OUT1F, Q5_0, Q5_1, Q5_2, Q5_3, b2,
                                         lnfg, lnfb, ln2g, ln2b, out2);
}

// Round 5
// 224.154 us; speedup vs baseline: 1.3789x; 1.0487x over previous
//
#include <hip/hip_runtime.h>

typedef unsigned short u16;
typedef __attribute__((ext_vector_type(4))) float f32x4;
typedef __attribute__((ext_vector_type(8))) __bf16 bf16x8;
typedef __attribute__((ext_vector_type(8))) unsigned short u16x8;
typedef __attribute__((ext_vector_type(4))) unsigned short u16x4;

// ---------- scalar bf16 helpers ----------
__device__ __forceinline__ u16 f2b(float f) {
    unsigned int u = __builtin_bit_cast(unsigned int, f);
    u = (u + 0x7FFFu + ((u >> 16) & 1u)) >> 16;
    return (u16)u;
}
__device__ __forceinline__ float b2f(u16 h) {
    unsigned int u = ((unsigned int)h) << 16;
    return __builtin_bit_cast(float, u);
}

// async global->LDS, 16B per lane; LDS dest is wave-uniform base (+lane*16 by HW)
__device__ __forceinline__ void gload_lds16(const u16* g, u16* l) {
    __builtin_amdgcn_global_load_lds(
        (const __attribute__((address_space(1))) void*)g,
        (__attribute__((address_space(3))) void*)l,
        16, 0, 0);
}

__device__ __forceinline__ bf16x8 lds_frag(const u16* p) {
    u16x8 t = *(const u16x8*)p;
    return __builtin_bit_cast(bf16x8, t);
}

#define FENCE asm volatile("" ::: "memory")
#define BARRIER do { FENCE; __builtin_amdgcn_s_barrier(); FENCE; \
                     __builtin_amdgcn_sched_barrier(0); } while (0)
#define LGKM0 do { asm volatile("s_waitcnt lgkmcnt(0)" ::: "memory"); \
                   __builtin_amdgcn_sched_barrier(0); } while (0)
#define WAIT_VM8 do { asm volatile("s_waitcnt vmcnt(8)" ::: "memory"); \
                      __builtin_amdgcn_sched_barrier(0); } while (0)
#define WAIT_VM4 do { asm volatile("s_waitcnt vmcnt(4)" ::: "memory"); \
                      __builtin_amdgcn_sched_barrier(0); } while (0)
#define WAIT_VM0 do { asm volatile("s_waitcnt vmcnt(0)" ::: "memory"); \
                      __builtin_amdgcn_sched_barrier(0); } while (0)

// ---------------- prep kernels ----------------
__global__ __launch_bounds__(256) void cast_x_kernel(const float* __restrict__ in,
                                                     u16* __restrict__ out) {
    int i = (blockIdx.x * 256 + threadIdx.x) * 4;
    float4 v = *(const float4*)&in[i];
    u16x4 o = { f2b(v.x), f2b(v.y), f2b(v.z), f2b(v.w) };
    *(u16x4*)&out[i] = o;
}

// WT[(sel*1024 + h*64 + e)][d] = w_sel[h][d][e]  — LDS-tiled transpose, coalesced both sides
__global__ __launch_bounds__(256) void tr_wqkv(const float* __restrict__ wq,
                                               const float* __restrict__ wk,
                                               const float* __restrict__ wv,
                                               u16* __restrict__ WT) {
    __shared__ float tile[32][33];
    int z = blockIdx.z;                    // 0..47 = sel*16 + h
    int sel = z >> 4, h = z & 15;
    const float* w = (sel == 0) ? wq : (sel == 1) ? wk : wv;
    w += (long)h * 65536;                  // [1024][64]
    int tx = threadIdx.x & 31, ty = threadIdx.x >> 5;
    int d0 = blockIdx.x * 32, e0 = blockIdx.y * 32;
#pragma unroll
    for (int i = 0; i < 32; i += 8)
        tile[ty + i][tx] = w[(long)(d0 + ty + i) * 64 + e0 + tx];
    __syncthreads();
#pragma unroll
    for (int i = 0; i < 32; i += 8)
        WT[((long)(sel * 1024 + h * 64 + e0 + ty + i)) * 1024 + d0 + tx] = f2b(tile[tx][ty + i]);
}

__global__ __launch_bounds__(256) void prep_bias(const float* __restrict__ bq,
                                                 const float* __restrict__ bk,
                                                 const float* __restrict__ bv,
                                                 float* __restrict__ BI) {
    int i = blockIdx.x * 256 + threadIdx.x;   // < 3072
    const float* b = (i < 1024) ? bq : (i < 2048) ? bk : bv;
    BI[i] = b[((i & 1023) >> 6) * 64 + (i & 63)];
}

// out[c][r] = (bf16) in[r][c]   (in: [R][C] f32)
__global__ __launch_bounds__(256) void transpose_cast(const float* __restrict__ in,
                                                      u16* __restrict__ out, int R, int C) {
    __shared__ float tile[32][33];
    int tx = threadIdx.x & 31, ty = threadIdx.x >> 5;   // 32 x 8
    int r0 = blockIdx.y * 32, c0 = blockIdx.x * 32;
#pragma unroll
    for (int i = 0; i < 32; i += 8)
        tile[ty + i][tx] = in[(long)(r0 + ty + i) * C + c0 + tx];
    __syncthreads();
#pragma unroll
    for (int i = 0; i < 32; i += 8)
        out[(long)(c0 + ty + i) * R + r0 + tx] = f2b(tile[tx][ty + i]);
}

// ---------------- templated tiled GEMM, phased counted-vmcnt pipeline ----------------
// C[M,N] = A[M,K] @ BT[N,K]^T. Tile BM=WM*MF*16, BN=WN*NF*16, BK=64, T=WM*WN*64 thr.
// MODE 1: +bias, bf16 out to Cb, f32 side-write cols>=1024 into KV (G1).
// MODE 2: +bias, relu, bf16 out (G4).
// MODE 4: 2-way split-K bf16 partials (no bias) to Q0/Q1 (G3, G5). nt must be EVEN.
// LDS: [rows][64 k] bf16/slot, byte-swizzle col^=(row&7)<<4 (inverse on global src, rule #21).
// Iteration: tile 2I from slot0, 2I+1 from slot1. Stage events (4 gloads each):
// e1=S1.h1(t0+1)@first phase (I>0); e2=S0.h0(t0+2)+VM4@last slot0 phase;
// e3=S0.h1(t0+2)@first slot1 phase; e4=S1.h0(t0+3)+VM4@last phase.
#define PHASEX(Sa, Sb, mh, kh, LOADB, STAGE_STMT, WAIT_STMT) do {             \
    if (LOADB) {                                                              \
        _Pragma("unroll") for (int n = 0; n < NF; ++n)                        \
            bfr[n] = lds_frag(&(Sb)[((brow0 + (n << 4)) << 6) +               \
                                    (eoff ^ ((kh) * 32))]);                   \
    }                                                                         \
    _Pragma("unroll") for (int m4 = 0; m4 < MFH; ++m4)                        \
        af[m4] = lds_frag(&(Sa)[((arow0 + (((mh) * MFH + m4) << 4)) << 6) +   \
                                (eoff ^ ((kh) * 32))]);                       \
    STAGE_STMT;                                                               \
    BARRIER;                                                                  \
    LGKM0;                                                                    \
    __builtin_amdgcn_s_setprio(1);                                            \
    _Pragma("unroll") for (int m4 = 0; m4 < MFH; ++m4)                        \
        _Pragma("unroll") for (int n = 0; n < NF; ++n)                        \
            acc[(mh) * MFH + m4][n] = __builtin_amdgcn_mfma_f32_16x16x32_bf16(\
                af[m4], bfr[n], acc[(mh) * MFH + m4][n], 0, 0, 0);            \
    __builtin_amdgcn_s_setprio(0);                                            \
    WAIT_STMT;                                                                \
    BARRIER;                                                                  \
} while (0)

template <int MODE, int WM, int WN, int MF, int NF, int MSPLIT>
__global__ __launch_bounds__(WM * WN * 64, 2) void gemmT(
    const u16* __restrict__ A, const u16* __restrict__ BT, const float* __restrict__ bias,
    u16* __restrict__ Cb, float* __restrict__ KV,
    u16* __restrict__ Q0, u16* __restrict__ Q1,
    int M, int N, int K, int lda, int ldb, int ldc, int kchunk) {
    constexpr int T   = WM * WN * 64;
    constexpr int BM  = WM * MF * 16;
    constexpr int BN  = WN * NF * 16;
    constexpr int RPI = T / 8;            // rows per gload instr
    constexpr int LA  = BM / RPI;         // gload instrs per A K-tile
    constexpr int LB  = BN / RPI;
    constexpr int EPI = T * 8;            // LDS elems per gload instr
    constexpr int MFH = MF / MSPLIT;
    __shared__ __align__(16) u16 As[2][BM * 64];
    __shared__ __align__(16) u16 Bs[2][BN * 64];
    const int tid = threadIdx.x;
    const int lane = tid & 63;
    const int wid = tid >> 6;
    const int wr = wid / WN, wc = wid % WN;
    const int ntile = N / BN;
    int bid = blockIdx.x;
    int kb = 0, ksz = K;
    u16* Pout = Q0;
    if (MODE == 4) {
        int tiles = (M / BM) * ntile;
        int sk = bid / tiles; bid -= sk * tiles;
        kb = sk * kchunk;
        int rem = K - kb; ksz = rem < kchunk ? rem : kchunk;
        Pout = sk ? Q1 : Q0;
    }
    const int bi = bid / ntile, bj = bid % ntile;
    const int brow = bi * BM, bcol = bj * BN;
    const int nt = ksz >> 6;              // BK=64 tiles; even by construction
    const int niter = nt >> 1;

    // ---- staging addressing (inverse-swizzled global source, linear LDS dest)
    const int srow = tid >> 3;                        // 0..RPI-1
    const int scol = ((tid & 7) ^ (srow & 7)) << 3;   // element offset in row
    const u16* ag = A + (long)(brow + srow) * lda + kb + scol;
    const u16* bg = BT + (long)(bcol + srow) * ldb + kb + scol;
    const long aI = (long)RPI * lda, bI = (long)RPI * ldb;
    const int sdst = tid << 3;

    // stage one half (A-half + B-half = (LA+LB)/2 = 4 gloads)
    auto STG = [&](int buf, int t, int half) {
#pragma unroll
        for (int j = 0; j < LA / 2; ++j)
            gload_lds16(ag + ((long)t << 6) + (half * (LA / 2) + j) * aI,
                        &As[buf][(half * (LA / 2) + j) * EPI + sdst]);
#pragma unroll
        for (int j = 0; j < LB / 2; ++j)
            gload_lds16(bg + ((long)t << 6) + (half * (LB / 2) + j) * bI,
                        &Bs[buf][(half * (LB / 2) + j) * EPI + sdst]);
    };

    f32x4 acc[MF][NF] = {};

    // ---- fragment read addressing (swizzled)
    const int ln15 = lane & 15;
    const int eoff = (((lane >> 4) << 3) ^ ((lane & 7) << 3));
    const int arow0 = wr * (MF * 16) + ln15;
    const int brow0 = wc * (NF * 16) + ln15;

    // ---- prologue: stage tile0 (slot0) + tile1 (slot1); wait tile0, keep tile1 in flight
    STG(0, 0, 0); STG(0, 0, 1);
    if (nt > 1) { STG(1, 1, 0); STG(1, 1, 1); WAIT_VM8; }
    else WAIT_VM0;
    BARRIER;

    for (int I = 0; I < niter; ++I) {
        const int t0 = 2 * I;
        const bool hn0 = (t0 + 2 < nt);
        const bool hn1 = (t0 + 3 < nt);
        const bool notlast = (I + 1 < niter);
        bf16x8 af[MFH], bfr[NF];
        if constexpr (MSPLIT == 2) {
            // ---- tile t0 from slot0
            PHASEX(As[0], Bs[0], 0, 0, true,  { if (I > 0) STG(1, t0 + 1, 1); }, {});
            PHASEX(As[0], Bs[0], 1, 0, false, {}, {});
            PHASEX(As[0], Bs[0], 0, 1, true,  {}, {});
            PHASEX(As[0], Bs[0], 1, 1, false, { if (hn0) STG(0, t0 + 2, 0); },
                   { if (hn0) WAIT_VM4; else WAIT_VM0; });
            // ---- tile t0+1 from slot1
            PHASEX(As[1], Bs[1], 0, 0, true,  { if (hn0) STG(0, t0 + 2, 1); }, {});
            PHASEX(As[1], Bs[1], 1, 0, false, {}, {});
            PHASEX(As[1], Bs[1], 0, 1, true,  {}, {});
            PHASEX(As[1], Bs[1], 1, 1, false, { if (hn1) STG(1, t0 + 3, 0); },
                   { if (notlast) { if (hn1) WAIT_VM4; else WAIT_VM0; } });
        } else {
            PHASEX(As[0], Bs[0], 0, 0, true,  { if (I > 0) STG(1, t0 + 1, 1); }, {});
            PHASEX(As[0], Bs[0], 0, 1, true,  { if (hn0) STG(0, t0 + 2, 0); },
                   { if (hn0) WAIT_VM4; else WAIT_VM0; });
            PHASEX(As[1], Bs[1], 0, 0, true,  { if (hn0) STG(0, t0 + 2, 1); }, {});
            PHASEX(As[1], Bs[1], 0, 1, true,  { if (hn1) STG(1, t0 + 3, 0); },
                   { if (notlast) { if (hn1) WAIT_VM4; else WAIT_VM0; } });
        }
    }

    // ---- epilogue
#pragma unroll
    for (int m = 0; m < MF; ++m) {
        int row = brow + wr * (MF * 16) + (m << 4) + ((lane >> 4) << 2);
#pragma unroll
        for (int n = 0; n < NF; ++n) {
            int col = bcol + wc * (NF * 16) + (n << 4) + ln15;
            float bv = (MODE == 4) ? 0.f : bias[col];
#pragma unroll
            for (int r = 0; r < 4; ++r) {
                float v = acc[m][n][r] + bv;
                long off = (long)(row + r) * ldc + col;
                if (MODE == 2) { v = v > 0.f ? v : 0.f; Cb[off] = f2b(v); }
                if (MODE == 1) {
                    Cb[off] = f2b(v);
                    if (col >= 1024) {
                        int c = col - 1024;
                        KV[(long)(c >> 10) * 4194304 + (long)(row + r) * 1024 + (c & 1023)] = v;
                    }
                }
                if (MODE == 4) Pout[off] = f2b(v);
            }
        }
    }
}

// ---------------- K^T V partial sums (t-chunked, f32 atomics) ----------------
__global__ __launch_bounds__(256) void ktv_partial(const u16* __restrict__ QKVB,
                                                   float* __restrict__ KTVF) {
    __shared__ __align__(16) u16 Ks[64 * 64];
    __shared__ __align__(16) u16 Vs[64 * 64];
    int tid = threadIdx.x;
    int tc = blockIdx.x, bh = blockIdx.y;
    int b = bh >> 4, h = bh & 15;
    int j = tid & 63, i0 = (tid >> 6) * 16;
    float acc[16] = {};
    for (int st = 0; st < 4; ++st) {
        int t0 = tc * 256 + st * 64;
        __syncthreads();
#pragma unroll
        for (int i = 0; i < 2; ++i) {
            int c = i * 256 + tid;
            long base = (long)(b * 2048 + t0 + (c >> 3)) * 3072 + h * 64 + (c & 7) * 8;
            *(u16x8*)&Ks[c * 8] = *(const u16x8*)&QKVB[base + 1024];
            *(u16x8*)&Vs[c * 8] = *(const u16x8*)&QKVB[base + 2048];
        }
        __syncthreads();
        for (int tt = 0; tt < 64; ++tt) {
            float vj = b2f(Vs[tt * 64 + j]);
            u16x8 k0 = *(const u16x8*)&Ks[tt * 64 + i0];
            u16x8 k1 = *(const u16x8*)&Ks[tt * 64 + i0 + 8];
#pragma unroll
            for (int r = 0; r < 8; ++r) acc[r] += b2f(k0[r]) * vj;
#pragma unroll
            for (int r = 0; r < 8; ++r) acc[r + 8] += b2f(k1[r]) * vj;
        }
    }
#pragma unroll
    for (int r = 0; r < 16; ++r)
        atomicAdd(&KTVF[bh * 4096 + (i0 + r) * 64 + j], acc[r]);
}

// KTVT[bh][n][k] = KTVF[bh][k][n] * 0.125 (fold 1/sqrt(64))
__global__ __launch_bounds__(256) void cast_ktv(const float* __restrict__ KTVF,
                                                u16* __restrict__ KTVT) {
    int idx = blockIdx.x * 256 + threadIdx.x;   // < 32*4096
    int bh = idx >> 12, r = idx & 4095;
    int n = r >> 6, k = r & 63;
    KTVT[idx] = f2b(KTVF[bh * 4096 + k * 64 + n] * 0.125f);
}

// ---------------- batched attn GEMM: cat[t, h*64+e'] = Q[t,:] @ KTVT[e',:] -------
__global__ __launch_bounds__(256) void attn_gemm(const u16* __restrict__ QKVB,
                                                 const u16* __restrict__ KTVT,
                                                 u16* __restrict__ cat) {
    __shared__ __align__(16) u16 Qs[64 * 64];
    __shared__ __align__(16) u16 Bs[64 * 64];
    int tid = threadIdx.x, wid = tid >> 6, lane = tid & 63;
    int rt = blockIdx.x, bh = blockIdx.y;
    int b = bh >> 4, h = bh & 15;
    long qbase = (long)(b * 2048 + rt * 64) * 3072 + h * 64;
#pragma unroll
    for (int i = 0; i < 2; ++i) {
        int c = i * 256 + tid;
        gload_lds16(QKVB + qbase + (c >> 3) * 3072 + (c & 7) * 8, &Qs[(i * 256 + wid * 64) * 8]);
        gload_lds16(KTVT + bh * 4096 + c * 8, &Bs[(i * 256 + wid * 64) * 8]);
    }
    __syncthreads();
    f32x4 acc[4] = {};
#pragma unroll
    for (int kk = 0; kk < 2; ++kk) {
        bf16x8 a = lds_frag(&Qs[(wid * 16 + (lane & 15)) * 64 + kk * 32 + (lane >> 4) * 8]);
#pragma unroll
        for (int n = 0; n < 4; ++n) {
            bf16x8 bb = lds_frag(&Bs[(n * 16 + (lane & 15)) * 64 + kk * 32 + (lane >> 4) * 8]);
            acc[n] = __builtin_amdgcn_mfma_f32_16x16x32_bf16(a, bb, acc[n], 0, 0, 0);
        }
    }
#pragma unroll
    for (int n = 0; n < 4; ++n)
#pragma unroll
        for (int r = 0; r < 4; ++r) {
            int row = rt * 64 + wid * 16 + (lane >> 4) * 4 + r;
            int col = h * 64 + n * 16 + (lane & 15);
            cat[(long)(b * 2048 + row) * 1024 + col] = f2b(acc[n][r]);
        }
}

// ---------------- layernorm kernels ----------------
__device__ __forceinline__ void block_reduce2(float& a, float& b) {
    __syncthreads();
#pragma unroll
    for (int off = 32; off; off >>= 1) {
        a += __shfl_down(a, off);
        b += __shfl_down(b, off);
    }
    __shared__ float sa[4], sb[4];
    int wid = threadIdx.x >> 6, lane = threadIdx.x & 63;
    if (lane == 0) { sa[wid] = a; sb[wid] = b; }
    __syncthreads();
    a = sa[0] + sa[1] + sa[2] + sa[3];
    b = sb[0] + sb[1] + sb[2] + sb[3];
}

// out1 = LN(x + (q0+q1 + bp)) ; write f32 + bf16  (q* = bf16 partials)
__global__ __launch_bounds__(256) void ln1_kernel(
    const float* __restrict__ x,
    const u16* __restrict__ q0, const u16* __restrict__ q1,
    const float* __restrict__ bp,
    const float* __restrict__ g, const float* __restrict__ bt,
    float* __restrict__ out1f, u16* __restrict__ out1b) {
    int row = blockIdx.x, tid = threadIdx.x;
    long base = (long)row * 1024 + tid * 4;
    float4 xv = *(const float4*)&x[base];
    u16x4 a0 = *(const u16x4*)&q0[base];
    u16x4 a1 = *(const u16x4*)&q1[base];
    float4 bb = *(const float4*)&bp[tid * 4];
    float xa[4] = { xv.x, xv.y, xv.z, xv.w };
    float bba[4] = { bb.x, bb.y, bb.z, bb.w };
    float s[4];
#pragma unroll
    for (int r = 0; r < 4; ++r)
        s[r] = xa[r] + b2f(a0[r]) + b2f(a1[r]) + bba[r];
    float sum = s[0] + s[1] + s[2] + s[3];
    float sq = s[0] * s[0] + s[1] * s[1] + s[2] * s[2] + s[3] * s[3];
    block_reduce2(sum, sq);
    float mu = sum * (1.f / 1024.f);
    float var = sq * (1.f / 1024.f) - mu * mu;
    float rs = rsqrtf(var + 1e-5f);
    float o0 = (s[0] - mu) * rs * g[tid * 4 + 0] + bt[tid * 4 + 0];
    float o1 = (s[1] - mu) * rs * g[tid * 4 + 1] + bt[tid * 4 + 1];
    float o2 = (s[2] - mu) * rs * g[tid * 4 + 2] + bt[tid * 4 + 2];
    float o3 = (s[3] - mu) * rs * g[tid * 4 + 3] + bt[tid * 4 + 3];
    float4 of; of.x = o0; of.y = o1; of.z = o2; of.w = o3;
    u16x4 ob = (u16x4){ f2b(o0), f2b(o1), f2b(o2), f2b(o3) };
    *(float4*)&out1f[base] = of;
    *(u16x4*)&out1b[base] = ob;
}

// ff = (q0+q1)+b2 (bf16 partials); ffo = LN(out1+ff); out2 = LN(out1+ffo)
__global__ __launch_bounds__(256) void lnf_kernel(
    const float* __restrict__ out1f,
    const u16* __restrict__ q0, const u16* __restrict__ q1,
    const float* __restrict__ b2,
    const float* __restrict__ lnfg, const float* __restrict__ lnfb,
    const float* __restrict__ ln2g, const float* __restrict__ ln2b,
    float* __restrict__ out2) {
    int row = blockIdx.x, tid = threadIdx.x;
    long base = (long)row * 1024 + tid * 4;
    float4 o1 = *(const float4*)&out1f[base];
    u16x4 a0 = *(const u16x4*)&q0[base];
    u16x4 a1 = *(const u16x4*)&q1[base];
    float4 bb = *(const float4*)&b2[tid * 4];
    float o1a[4] = { o1.x, o1.y, o1.z, o1.w };
    float bba[4] = { bb.x, bb.y, bb.z, bb.w };
    float s1[4];
#pragma unroll
    for (int r = 0; r < 4; ++r)
        s1[r] = o1a[r] + b2f(a0[r]) + b2f(a1[r]) + bba[r];
    float sum = s1[0] + s1[1] + s1[2] + s1[3];
    float sq = s1[0] * s1[0] + s1[1] * s1[1] + s1[2] * s1[2] + s1[3] * s1[3];
    block_reduce2(sum, sq);
    float mu = sum * (1.f / 1024.f);
    float rs = rsqrtf(sq * (1.f / 1024.f) - mu * mu + 1e-5f);
    float s2[4];
#pragma unroll
    for (int r = 0; r < 4; ++r) {
        float ffo = (s1[r] - mu) * rs * lnfg[tid * 4 + r] + lnfb[tid * 4 + r];
        s2[r] = o1a[r] + ffo;
    }
    float sum2 = s2[0] + s2[1] + s2[2] + s2[3];
    float sq2 = s2[0] * s2[0] + s2[1] * s2[1] + s2[2] * s2[2] + s2[3] * s2[3];
    block_reduce2(sum2, sq2);
    float mu2 = sum2 * (1.f / 1024.f);
    float rs2 = rsqrtf(sq2 * (1.f / 1024.f) - mu2 * mu2 + 1e-5f);
    float4 o;
    o.x = (s2[0] - mu2) * rs2 * ln2g[tid * 4 + 0] + ln2b[tid * 4 + 0];
    o.y = (s2[1] - mu2) * rs2 * ln2g[tid * 4 + 1] + ln2b[tid * 4 + 1];
    o.z = (s2[2] - mu2) * rs2 * ln2g[tid * 4 + 2] + ln2b[tid * 4 + 2];
    o.w = (s2[3] - mu2) * rs2 * ln2g[tid * 4 + 3] + ln2b[tid * 4 + 3];
    *(float4*)&out2[base] = o;
}

// ---------------- launcher ----------------
extern "C" void kernel_launch(void* const* d_in, const int* in_sizes, int n_in,
                              void* d_out, int out_size, void* d_ws, size_t ws_size,
                              hipStream_t stream) {
    const float* x    = (const float*)d_in[0];
    const float* wq   = (const float*)d_in[1];
    const float* bq   = (const float*)d_in[2];
    const float* wk   = (const float*)d_in[3];
    const float* bk   = (const float*)d_in[4];
    const float* wv   = (const float*)d_in[5];
    const float* bv   = (const float*)d_in[6];
    const float* wp   = (const float*)d_in[7];
    const float* bp   = (const float*)d_in[8];
    const float* w1   = (const float*)d_in[9];
    const float* b1   = (const float*)d_in[10];
    const float* w2   = (const float*)d_in[11];
    const float* b2   = (const float*)d_in[12];
    const float* ln1g = (const float*)d_in[13];
    const float* ln1b = (const float*)d_in[14];
    const float* lnfg = (const float*)d_in[15];
    const float* lnfb = (const float*)d_in[16];
    const float* ln2g = (const float*)d_in[17];
    const float* ln2b = (const float*)d_in[18];

    float* out2 = (float*)d_out;
    float* kv   = (float*)d_out + 4194304;   // Kc then Vc

    // workspace layout (bytes). Liveness:
    char* ws = (char*)d_ws;
    u16*   XB     = (u16*)  (ws + 0);          // 8 MB (dead after G1); CAT (dead after G3); Q5_0
    u16*   CAT    = XB;
    u16*   WQKVT  = (u16*)  (ws + 8388608);    // 6.3 MB (dead after G1)
    float* BQKV   = (float*)(ws + 14680064);   // 12 KB (dead after G1)
    u16*   WPT    = (u16*)  (ws + 14692352);   // 2 MB (dead after G3)
    u16*   W1T    = (u16*)  (ws + 16789504);   // 8 MB (dead after G4)
    u16*   W2T    = (u16*)  (ws + 25178112);   // 8 MB (live through G5)
    float* KTVF   = (float*)(ws + 33566720);   // 512 KB
    u16*   KTVT   = (u16*)  (ws + 34091008);   // 256 KB
    u16*   QKVB   = (u16*)  (ws + 34353152);   // 24 MB (dead after attn); OUT1B (dead after G4)
    u16*   OUT1B  = QKVB;
    u16*   Q3_0   = (u16*)  (ws + 59518976);   // 8 MB (dead after ln1)
    u16*   Q3_1   = (u16*)  (ws + 67907584);   // 8 MB (dead after ln1)
    float* OUT1F  = (float*)(ws + 76296192);   // 16 MB (live to lnf)
    u16*   H1     = (u16*)  (ws + 93073408);   // 32 MB (live through G5)
    u16*   Q5_0   = (u16*)  (ws + 0);          // 8 MB (over XB/CAT, dead after G3)
    u16*   Q5_1   = (u16*)  (ws + 34353152);   // 8 MB (over OUT1B, dead after G4)
    (void)ws_size; (void)in_sizes; (void)n_in; (void)out_size;

    hipMemsetAsync(KTVF, 0, 32 * 4096 * 4, stream);
    cast_x_kernel<<<4096, 256, 0, stream>>>(x, XB);
    tr_wqkv<<<dim3(32, 2, 48), 256, 0, stream>>>(wq, wk, wv, WQKVT);
    prep_bias<<<12, 256, 0, stream>>>(bq, bk, bv, BQKV);
    transpose_cast<<<dim3(32, 32), 256, 0, stream>>>(wp, WPT, 1024, 1024);
    transpose_cast<<<dim3(128, 32), 256, 0, stream>>>(w1, W1T, 1024, 4096);
    transpose_cast<<<dim3(32, 128), 256, 0, stream>>>(w2, W2T, 4096, 1024);

    // G1: QKV = X @ Wqkv + b  (128x384 tile -> grid 32x8 = 256, full fill)
    gemmT<1, 2, 4, 4, 6, 2><<<256, 512, 0, stream>>>(
        XB, WQKVT, BQKV, QKVB, kv, nullptr, nullptr,
        4096, 3072, 1024, 1024, 1024, 3072, 0);
    ktv_partial<<<dim3(8, 32), 256, 0, stream>>>(QKVB, KTVF);
    cast_ktv<<<512, 256, 0, stream>>>(KTVF, KTVT);
    attn_gemm<<<dim3(32, 32), 256, 0, stream>>>(QKVB, KTVT, CAT);

    // G3: out = cat @ wp (128x128 tile, split-K x2, 512 blocks -> 2 blocks/CU)
    gemmT<4, 2, 2, 4, 4, 1><<<512, 256, 0, stream>>>(
        CAT, WPT, nullptr, nullptr, nullptr, Q3_0, Q3_1,
        4096, 1024, 1024, 1024, 1024, 1024, 512);
    ln1_kernel<<<4096, 256, 0, stream>>>(x, Q3_0, Q3_1, bp, ln1g, ln1b, OUT1F, OUT1B);

    // G4: h1 = relu(out1 @ w1 + b1) (256x256 tile, grid 256)
    gemmT<2, 2, 4, 8, 4, 2><<<256, 512, 0, stream>>>(
        OUT1B, W1T, b1, H1, nullptr, nullptr, nullptr,
        4096, 4096, 1024, 1024, 1024, 4096, 0);
    // G5: ff = h1 @ w2 (128x128 tile, split-K x2 over K=4096, 512 blocks -> 2 blocks/CU)
    gemmT<4, 2, 2, 4, 4, 1><<<512, 256, 0, stream>>>(
        H1, W2T, nullptr, nullptr, nullptr, Q5_0, Q5_1,
        4096, 1024, 4096, 4096, 4096, 1024, 2048);
    lnf_kernel<<<4096, 256, 0, stream>>>(OUT1F, Q5_0, Q5_1, b2,
                                         lnfg, lnfb, ln2g, ln2b, out2);
}

// Round 6
// 220.531 us; speedup vs baseline: 1.4016x; 1.0164x over previous
//
#include <hip/hip_runtime.h>

typedef unsigned short u16;
typedef __attribute__((ext_vector_type(4))) float f32x4;
typedef __attribute__((ext_vector_type(8))) __bf16 bf16x8;
typedef __attribute__((ext_vector_type(8))) unsigned short u16x8;
typedef __attribute__((ext_vector_type(4))) unsigned short u16x4;

// ---------- scalar bf16 helpers ----------
__device__ __forceinline__ u16 f2b(float f) {
    unsigned int u = __builtin_bit_cast(unsigned int, f);
    u = (u + 0x7FFFu + ((u >> 16) & 1u)) >> 16;
    return (u16)u;
}
__device__ __forceinline__ float b2f(u16 h) {
    unsigned int u = ((unsigned int)h) << 16;
    return __builtin_bit_cast(float, u);
}

// async global->LDS, 16B per lane; LDS dest is wave-uniform base (+lane*16 by HW)
__device__ __forceinline__ void gload_lds16(const u16* g, u16* l) {
    __builtin_amdgcn_global_load_lds(
        (const __attribute__((address_space(1))) void*)g,
        (__attribute__((address_space(3))) void*)l,
        16, 0, 0);
}

__device__ __forceinline__ bf16x8 lds_frag(const u16* p) {
    u16x8 t = *(const u16x8*)p;
    return __builtin_bit_cast(bf16x8, t);
}

#define FENCE asm volatile("" ::: "memory")
#define BARRIER do { FENCE; __builtin_amdgcn_s_barrier(); FENCE; \
                     __builtin_amdgcn_sched_barrier(0); } while (0)
#define LGKM0 do { asm volatile("s_waitcnt lgkmcnt(0)" ::: "memory"); \
                   __builtin_amdgcn_sched_barrier(0); } while (0)
#define WAIT_VM8 do { asm volatile("s_waitcnt vmcnt(8)" ::: "memory"); \
                      __builtin_amdgcn_sched_barrier(0); } while (0)
#define WAIT_VM4 do { asm volatile("s_waitcnt vmcnt(4)" ::: "memory"); \
                      __builtin_amdgcn_sched_barrier(0); } while (0)
#define WAIT_VM0 do { asm volatile("s_waitcnt vmcnt(0)" ::: "memory"); \
                      __builtin_amdgcn_sched_barrier(0); } while (0)

// ---------------- prep kernels ----------------
__global__ __launch_bounds__(256) void cast_x_kernel(const float* __restrict__ in,
                                                     u16* __restrict__ out) {
    int i = (blockIdx.x * 256 + threadIdx.x) * 4;
    float4 v = *(const float4*)&in[i];
    u16x4 o = { f2b(v.x), f2b(v.y), f2b(v.z), f2b(v.w) };
    *(u16x4*)&out[i] = o;
}

// WT[(sel*1024 + h*64 + e)][d] = w_sel[h][d][e]  — LDS-tiled transpose
__global__ __launch_bounds__(256) void tr_wqkv(const float* __restrict__ wq,
                                               const float* __restrict__ wk,
                                               const float* __restrict__ wv,
                                               u16* __restrict__ WT) {
    __shared__ float tile[32][33];
    int z = blockIdx.z;                    // 0..47 = sel*16 + h
    int sel = z >> 4, h = z & 15;
    const float* w = (sel == 0) ? wq : (sel == 1) ? wk : wv;
    w += (long)h * 65536;                  // [1024][64]
    int tx = threadIdx.x & 31, ty = threadIdx.x >> 5;
    int d0 = blockIdx.x * 32, e0 = blockIdx.y * 32;
#pragma unroll
    for (int i = 0; i < 32; i += 8)
        tile[ty + i][tx] = w[(long)(d0 + ty + i) * 64 + e0 + tx];
    __syncthreads();
#pragma unroll
    for (int i = 0; i < 32; i += 8)
        WT[((long)(sel * 1024 + h * 64 + e0 + ty + i)) * 1024 + d0 + tx] = f2b(tile[tx][ty + i]);
}

__global__ __launch_bounds__(256) void prep_bias(const float* __restrict__ bq,
                                                 const float* __restrict__ bk,
                                                 const float* __restrict__ bv,
                                                 float* __restrict__ BI) {
    int i = blockIdx.x * 256 + threadIdx.x;   // < 3072
    const float* b = (i < 1024) ? bq : (i < 2048) ? bk : bv;
    BI[i] = b[((i & 1023) >> 6) * 64 + (i & 63)];
}

// out[c][r] = (bf16) in[r][c]   (in: [R][C] f32)
__global__ __launch_bounds__(256) void transpose_cast(const float* __restrict__ in,
                                                      u16* __restrict__ out, int R, int C) {
    __shared__ float tile[32][33];
    int tx = threadIdx.x & 31, ty = threadIdx.x >> 5;   // 32 x 8
    int r0 = blockIdx.y * 32, c0 = blockIdx.x * 32;
#pragma unroll
    for (int i = 0; i < 32; i += 8)
        tile[ty + i][tx] = in[(long)(r0 + ty + i) * C + c0 + tx];
    __syncthreads();
#pragma unroll
    for (int i = 0; i < 32; i += 8)
        out[(long)(c0 + ty + i) * R + r0 + tx] = f2b(tile[tx][ty + i]);
}

// Kc/Vc f32 expand from QKVB cols 1024..3071 (values bf16-exact)
__global__ __launch_bounds__(256) void kv_expand(const u16* __restrict__ QKVB,
                                                 float* __restrict__ kv) {
    int idx = blockIdx.x * 256 + threadIdx.x;  // 4096*2048/8 = 1,048,576
    int row = idx >> 8;
    int co = (idx & 255) * 8;                  // col in [0,2048), 8-aligned
    u16x8 v = *(const u16x8*)&QKVB[(long)row * 3072 + 1024 + co];
    float4 f0 = { b2f(v[0]), b2f(v[1]), b2f(v[2]), b2f(v[3]) };
    float4 f1 = { b2f(v[4]), b2f(v[5]), b2f(v[6]), b2f(v[7]) };
    long base = (long)(co >> 10) * 4194304 + (long)row * 1024 + (co & 1023);
    *(float4*)&kv[base] = f0;
    *(float4*)&kv[base + 4] = f1;
}

// ---------------- templated tiled GEMM, phased counted-vmcnt pipeline ----------------
// C[M,N] = A[M,K] @ BT[N,K]^T. Tile BM=WM*MF*16, BN=WN*NF*16, BK=64, T=WM*WN*64 thr.
// MODE 1: +bias, bf16 out (G1). MODE 2: +bias, relu, bf16 out (G4).
// MODE 4: 2-way split-K bf16 partials (no bias) to Q0/Q1 (G3, G5). nt must be EVEN.
// LDS: [rows][64 k] bf16/slot, byte-swizzle col^=(row&7)<<4 (inverse on global src).
// Epilogue: acc -> bf16 via LDS repack -> fully coalesced u16x8 global stores.
// Grid: XCD-chunked bijective swizzle + column-outer decode (each XCD owns 1-2
// B column-panels -> B slice L2-resident).
#define PHASEX(Sa, Sb, mh, kh, LOADB, STAGE_STMT, WAIT_STMT) do {             \
    if (LOADB) {                                                              \
        _Pragma("unroll") for (int n = 0; n < NF; ++n)                        \
            bfr[n] = lds_frag(&(Sb)[((brow0 + (n << 4)) << 6) +               \
                                    (eoff ^ ((kh) * 32))]);                   \
    }                                                                         \
    _Pragma("unroll") for (int m4 = 0; m4 < MFH; ++m4)                        \
        af[m4] = lds_frag(&(Sa)[((arow0 + (((mh) * MFH + m4) << 4)) << 6) +   \
                                (eoff ^ ((kh) * 32))]);                       \
    STAGE_STMT;                                                               \
    BARRIER;                                                                  \
    LGKM0;                                                                    \
    __builtin_amdgcn_s_setprio(1);                                            \
    _Pragma("unroll") for (int m4 = 0; m4 < MFH; ++m4)                        \
        _Pragma("unroll") for (int n = 0; n < NF; ++n)                        \
            acc[(mh) * MFH + m4][n] = __builtin_amdgcn_mfma_f32_16x16x32_bf16(\
                af[m4], bfr[n], acc[(mh) * MFH + m4][n], 0, 0, 0);            \
    __builtin_amdgcn_s_setprio(0);                                            \
    WAIT_STMT;                                                                \
    BARRIER;                                                                  \
} while (0)

template <int MODE, int WM, int WN, int MF, int NF, int MSPLIT>
__global__ __launch_bounds__(WM * WN * 64, 2) void gemmT(
    const u16* __restrict__ A, const u16* __restrict__ BT, const float* __restrict__ bias,
    u16* __restrict__ Cb, u16* __restrict__ Q0, u16* __restrict__ Q1,
    int M, int N, int K, int lda, int ldb, int ldc, int kchunk) {
    constexpr int T   = WM * WN * 64;
    constexpr int BM  = WM * MF * 16;
    constexpr int BN  = WN * NF * 16;
    constexpr int RPI = T / 8;            // rows per gload instr
    constexpr int LA  = BM / RPI;         // gload instrs per A K-tile
    constexpr int LB  = BN / RPI;
    constexpr int EPI = T * 8;            // LDS elems per gload instr
    constexpr int MFH = MF / MSPLIT;
    constexpr int ASZ = BM * 64, BSZ = BN * 64;
    __shared__ __align__(16) u16 SMEM[2 * ASZ + 2 * BSZ];
    u16* As0 = SMEM;
    u16* As1 = SMEM + ASZ;
    u16* Bs0 = SMEM + 2 * ASZ;
    u16* Bs1 = SMEM + 2 * ASZ + BSZ;
    const int tid = threadIdx.x;
    const int lane = tid & 63;
    const int wid = tid >> 6;
    const int wr = wid / WN, wc = wid % WN;
    const int ntile = N / BN;
    const int mtile = M / BM;
    int bid = blockIdx.x;
    int kb = 0, ksz = K;
    u16* Pout = Q0;
    if (MODE == 4) {
        int tiles = mtile * ntile;
        int sk = bid / tiles; bid -= sk * tiles;
        kb = sk * kchunk;
        int rem = K - kb; ksz = rem < kchunk ? rem : kchunk;
        Pout = sk ? Q1 : Q0;
    }
    // XCD-chunked bijective swizzle (tile count is a multiple of 8)
    {
        int q = (mtile * ntile) >> 3;
        bid = (bid & 7) * q + (bid >> 3);
    }
    const int bj = bid / mtile, bi = bid % mtile;   // column-outer: XCD owns few B panels
    const int brow = bi * BM, bcol = bj * BN;
    const int nt = ksz >> 6;              // BK=64 tiles; even by construction
    const int niter = nt >> 1;

    // ---- staging addressing (inverse-swizzled global source, linear LDS dest)
    const int srow = tid >> 3;                        // 0..RPI-1
    const int scol = ((tid & 7) ^ (srow & 7)) << 3;   // element offset in row
    const u16* ag = A + (long)(brow + srow) * lda + kb + scol;
    const u16* bg = BT + (long)(bcol + srow) * ldb + kb + scol;
    const long aI = (long)RPI * lda, bI = (long)RPI * ldb;
    const int sdst = tid << 3;

    // stage one half (A-half + B-half = (LA+LB)/2 = 4 gloads)
    auto STG = [&](u16* lA, u16* lB, int t, int half) {
#pragma unroll
        for (int j = 0; j < LA / 2; ++j)
            gload_lds16(ag + ((long)t << 6) + (half * (LA / 2) + j) * aI,
                        &lA[(half * (LA / 2) + j) * EPI + sdst]);
#pragma unroll
        for (int j = 0; j < LB / 2; ++j)
            gload_lds16(bg + ((long)t << 6) + (half * (LB / 2) + j) * bI,
                        &lB[(half * (LB / 2) + j) * EPI + sdst]);
    };

    f32x4 acc[MF][NF] = {};

    // ---- fragment read addressing (swizzled)
    const int ln15 = lane & 15;
    const int eoff = (((lane >> 4) << 3) ^ ((lane & 7) << 3));
    const int arow0 = wr * (MF * 16) + ln15;
    const int brow0 = wc * (NF * 16) + ln15;

    // ---- prologue
    STG(As0, Bs0, 0, 0); STG(As0, Bs0, 0, 1);
    if (nt > 1) { STG(As1, Bs1, 1, 0); STG(As1, Bs1, 1, 1); WAIT_VM8; }
    else WAIT_VM0;
    BARRIER;

    for (int I = 0; I < niter; ++I) {
        const int t0 = 2 * I;
        const bool hn0 = (t0 + 2 < nt);
        const bool hn1 = (t0 + 3 < nt);
        const bool notlast = (I + 1 < niter);
        bf16x8 af[MFH], bfr[NF];
        if constexpr (MSPLIT == 2) {
            PHASEX(As0, Bs0, 0, 0, true,  { if (I > 0) STG(As1, Bs1, t0 + 1, 1); }, {});
            PHASEX(As0, Bs0, 1, 0, false, {}, {});
            PHASEX(As0, Bs0, 0, 1, true,  {}, {});
            PHASEX(As0, Bs0, 1, 1, false, { if (hn0) STG(As0, Bs0, t0 + 2, 0); },
                   { if (hn0) WAIT_VM4; else WAIT_VM0; });
            PHASEX(As1, Bs1, 0, 0, true,  { if (hn0) STG(As0, Bs0, t0 + 2, 1); }, {});
            PHASEX(As1, Bs1, 1, 0, false, {}, {});
            PHASEX(As1, Bs1, 0, 1, true,  {}, {});
            PHASEX(As1, Bs1, 1, 1, false, { if (hn1) STG(As1, Bs1, t0 + 3, 0); },
                   { if (notlast) { if (hn1) WAIT_VM4; else WAIT_VM0; } });
        } else {
            PHASEX(As0, Bs0, 0, 0, true,  { if (I > 0) STG(As1, Bs1, t0 + 1, 1); }, {});
            PHASEX(As0, Bs0, 0, 1, true,  { if (hn0) STG(As0, Bs0, t0 + 2, 0); },
                   { if (hn0) WAIT_VM4; else WAIT_VM0; });
            PHASEX(As1, Bs1, 0, 0, true,  { if (hn0) STG(As0, Bs0, t0 + 2, 1); }, {});
            PHASEX(As1, Bs1, 0, 1, true,  { if (hn1) STG(As1, Bs1, t0 + 3, 0); },
                   { if (notlast) { if (hn1) WAIT_VM4; else WAIT_VM0; } });
        }
    }

    // ---- epilogue: repack through LDS for coalesced stores
    // (loop ended with BARRIER; staging LDS is dead, reuse as C tile [BM][BN] bf16)
    const int crow0 = wr * (MF * 16), ccol0 = wc * (NF * 16);
#pragma unroll
    for (int m = 0; m < MF; ++m) {
        int rbase = crow0 + (m << 4) + ((lane >> 4) << 2);
#pragma unroll
        for (int n = 0; n < NF; ++n) {
            int col = ccol0 + (n << 4) + ln15;
            float bv = (MODE == 4) ? 0.f : bias[bcol + col];
#pragma unroll
            for (int r = 0; r < 4; ++r) {
                float v = acc[m][n][r] + bv;
                if (MODE == 2) v = v > 0.f ? v : 0.f;
                SMEM[(rbase + r) * BN + col] = f2b(v);
            }
        }
    }
    LGKM0;
    BARRIER;
    u16* outp = (MODE == 4) ? Pout : Cb;
    constexpr int CHT = BM * BN / 8 / T;
#pragma unroll
    for (int k = 0; k < CHT; ++k) {
        int c = tid + k * T;
        int row = c / (BN / 8), co = (c % (BN / 8)) * 8;
        u16x8 vv = *(const u16x8*)&SMEM[row * BN + co];
        *(u16x8*)&outp[(long)(brow + row) * ldc + bcol + co] = vv;
    }
}

// ---------------- K^T V partial sums (t-chunked, f32 atomics) ----------------
__global__ __launch_bounds__(256) void ktv_partial(const u16* __restrict__ QKVB,
                                                   float* __restrict__ KTVF) {
    __shared__ __align__(16) u16 Ks[64 * 64];
    __shared__ __align__(16) u16 Vs[64 * 64];
    int tid = threadIdx.x;
    int tc = blockIdx.x, bh = blockIdx.y;
    int b = bh >> 4, h = bh & 15;
    int j = tid & 63, i0 = (tid >> 6) * 16;
    float acc[16] = {};
    for (int st = 0; st < 4; ++st) {
        int t0 = tc * 256 + st * 64;
        __syncthreads();
#pragma unroll
        for (int i = 0; i < 2; ++i) {
            int c = i * 256 + tid;
            long base = (long)(b * 2048 + t0 + (c >> 3)) * 3072 + h * 64 + (c & 7) * 8;
            *(u16x8*)&Ks[c * 8] = *(const u16x8*)&QKVB[base + 1024];
            *(u16x8*)&Vs[c * 8] = *(const u16x8*)&QKVB[base + 2048];
        }
        __syncthreads();
        for (int tt = 0; tt < 64; ++tt) {
            float vj = b2f(Vs[tt * 64 + j]);
            u16x8 k0 = *(const u16x8*)&Ks[tt * 64 + i0];
            u16x8 k1 = *(const u16x8*)&Ks[tt * 64 + i0 + 8];
#pragma unroll
            for (int r = 0; r < 8; ++r) acc[r] += b2f(k0[r]) * vj;
#pragma unroll
            for (int r = 0; r < 8; ++r) acc[r + 8] += b2f(k1[r]) * vj;
        }
    }
#pragma unroll
    for (int r = 0; r < 16; ++r)
        atomicAdd(&KTVF[bh * 4096 + (i0 + r) * 64 + j], acc[r]);
}

// KTVT[bh][n][k] = KTVF[bh][k][n] * 0.125 (fold 1/sqrt(64))
__global__ __launch_bounds__(256) void cast_ktv(const float* __restrict__ KTVF,
                                                u16* __restrict__ KTVT) {
    int idx = blockIdx.x * 256 + threadIdx.x;   // < 32*4096
    int bh = idx >> 12, r = idx & 4095;
    int n = r >> 6, k = r & 63;
    KTVT[idx] = f2b(KTVF[bh * 4096 + k * 64 + n] * 0.125f);
}

// ---------------- batched attn GEMM: cat[t, h*64+e'] = Q[t,:] @ KTVT[e',:] -------
__global__ __launch_bounds__(256) void attn_gemm(const u16* __restrict__ QKVB,
                                                 const u16* __restrict__ KTVT,
                                                 u16* __restrict__ cat) {
    __shared__ __align__(16) u16 Qs[64 * 64];
    __shared__ __align__(16) u16 Bs[64 * 64];
    int tid = threadIdx.x, wid = tid >> 6, lane = tid & 63;
    int rt = blockIdx.x, bh = blockIdx.y;
    int b = bh >> 4, h = bh & 15;
    long qbase = (long)(b * 2048 + rt * 64) * 3072 + h * 64;
#pragma unroll
    for (int i = 0; i < 2; ++i) {
        int c = i * 256 + tid;
        gload_lds16(QKVB + qbase + (c >> 3) * 3072 + (c & 7) * 8, &Qs[(i * 256 + wid * 64) * 8]);
        gload_lds16(KTVT + bh * 4096 + c * 8, &Bs[(i * 256 + wid * 64) * 8]);
    }
    __syncthreads();
    f32x4 acc[4] = {};
#pragma unroll
    for (int kk = 0; kk < 2; ++kk) {
        bf16x8 a = lds_frag(&Qs[(wid * 16 + (lane & 15)) * 64 + kk * 32 + (lane >> 4) * 8]);
#pragma unroll
        for (int n = 0; n < 4; ++n) {
            bf16x8 bb = lds_frag(&Bs[(n * 16 + (lane & 15)) * 64 + kk * 32 + (lane >> 4) * 8]);
            acc[n] = __builtin_amdgcn_mfma_f32_16x16x32_bf16(a, bb, acc[n], 0, 0, 0);
        }
    }
#pragma unroll
    for (int n = 0; n < 4; ++n)
#pragma unroll
        for (int r = 0; r < 4; ++r) {
            int row = rt * 64 + wid * 16 + (lane >> 4) * 4 + r;
            int col = h * 64 + n * 16 + (lane & 15);
            cat[(long)(b * 2048 + row) * 1024 + col] = f2b(acc[n][r]);
        }
}

// ---------------- layernorm kernels ----------------
__device__ __forceinline__ void block_reduce2(float& a, float& b) {
    __syncthreads();
#pragma unroll
    for (int off = 32; off; off >>= 1) {
        a += __shfl_down(a, off);
        b += __shfl_down(b, off);
    }
    __shared__ float sa[4], sb[4];
    int wid = threadIdx.x >> 6, lane = threadIdx.x & 63;
    if (lane == 0) { sa[wid] = a; sb[wid] = b; }
    __syncthreads();
    a = sa[0] + sa[1] + sa[2] + sa[3];
    b = sb[0] + sb[1] + sb[2] + sb[3];
}

// out1 = LN(x + (q0+q1 + bp)) ; write f32 + bf16  (q* = bf16 partials)
__global__ __launch_bounds__(256) void ln1_kernel(
    const float* __restrict__ x,
    const u16* __restrict__ q0, const u16* __restrict__ q1,
    const float* __restrict__ bp,
    const float* __restrict__ g, const float* __restrict__ bt,
    float* __restrict__ out1f, u16* __restrict__ out1b) {
    int row = blockIdx.x, tid = threadIdx.x;
    long base = (long)row * 1024 + tid * 4;
    float4 xv = *(const float4*)&x[base];
    u16x4 a0 = *(const u16x4*)&q0[base];
    u16x4 a1 = *(const u16x4*)&q1[base];
    float4 bb = *(const float4*)&bp[tid * 4];
    float xa[4] = { xv.x, xv.y, xv.z, xv.w };
    float bba[4] = { bb.x, bb.y, bb.z, bb.w };
    float s[4];
#pragma unroll
    for (int r = 0; r < 4; ++r)
        s[r] = xa[r] + b2f(a0[r]) + b2f(a1[r]) + bba[r];
    float sum = s[0] + s[1] + s[2] + s[3];
    float sq = s[0] * s[0] + s[1] * s[1] + s[2] * s[2] + s[3] * s[3];
    block_reduce2(sum, sq);
    float mu = sum * (1.f / 1024.f);
    float var = sq * (1.f / 1024.f) - mu * mu;
    float rs = rsqrtf(var + 1e-5f);
    float o0 = (s[0] - mu) * rs * g[tid * 4 + 0] + bt[tid * 4 + 0];
    float o1 = (s[1] - mu) * rs * g[tid * 4 + 1] + bt[tid * 4 + 1];
    float o2 = (s[2] - mu) * rs * g[tid * 4 + 2] + bt[tid * 4 + 2];
    float o3 = (s[3] - mu) * rs * g[tid * 4 + 3] + bt[tid * 4 + 3];
    float4 of; of.x = o0; of.y = o1; of.z = o2; of.w = o3;
    u16x4 ob = (u16x4){ f2b(o0), f2b(o1), f2b(o2), f2b(o3) };
    *(float4*)&out1f[base] = of;
    *(u16x4*)&out1b[base] = ob;
}

// ff = (q0+q1)+b2 (bf16 partials); ffo = LN(out1+ff); out2 = LN(out1+ffo)
__global__ __launch_bounds__(256) void lnf_kernel(
    const float* __restrict__ out1f,
    const u16* __restrict__ q0, const u16* __restrict__ q1,
    const float* __restrict__ b2,
    const float* __restrict__ lnfg, const float* __restrict__ lnfb,
    const float* __restrict__ ln2g, const float* __restrict__ ln2b,
    float* __restrict__ out2) {
    int row = blockIdx.x, tid = threadIdx.x;
    long base = (long)row * 1024 + tid * 4;
    float4 o1 = *(const float4*)&out1f[base];
    u16x4 a0 = *(const u16x4*)&q0[base];
    u16x4 a1 = *(const u16x4*)&q1[base];
    float4 bb = *(const float4*)&b2[tid * 4];
    float o1a[4] = { o1.x, o1.y, o1.z, o1.w };
    float bba[4] = { bb.x, bb.y, bb.z, bb.w };
    float s1[4];
#pragma unroll
    for (int r = 0; r < 4; ++r)
        s1[r] = o1a[r] + b2f(a0[r]) + b2f(a1[r]) + bba[r];
    float sum = s1[0] + s1[1] + s1[2] + s1[3];
    float sq = s1[0] * s1[0] + s1[1] * s1[1] + s1[2] * s1[2] + s1[3] * s1[3];
    block_reduce2(sum, sq);
    float mu = sum * (1.f / 1024.f);
    float rs = rsqrtf(sq * (1.f / 1024.f) - mu * mu + 1e-5f);
    float s2[4];
#pragma unroll
    for (int r = 0; r < 4; ++r) {
        float ffo = (s1[r] - mu) * rs * lnfg[tid * 4 + r] + lnfb[tid * 4 + r];
        s2[r] = o1a[r] + ffo;
    }
    float sum2 = s2[0] + s2[1] + s2[2] + s2[3];
    float sq2 = s2[0] * s2[0] + s2[1] * s2[1] + s2[2] * s2[2] + s2[3] * s2[3];
    block_reduce2(sum2, sq2);
    float mu2 = sum2 * (1.f / 1024.f);
    float rs2 = rsqrtf(sq2 * (1.f / 1024.f) - mu2 * mu2 + 1e-5f);
    float4 o;
    o.x = (s2[0] - mu2) * rs2 * ln2g[tid * 4 + 0] + ln2b[tid * 4 + 0];
    o.y = (s2[1] - mu2) * rs2 * ln2g[tid * 4 + 1] + ln2b[tid * 4 + 1];
    o.z = (s2[2] - mu2) * rs2 * ln2g[tid * 4 + 2] + ln2b[tid * 4 + 2];
    o.w = (s2[3] - mu2) * rs2 * ln2g[tid * 4 + 3] + ln2b[tid * 4 + 3];
    *(float4*)&out2[base] = o;
}

// ---------------- launcher ----------------
extern "C" void kernel_launch(void* const* d_in, const int* in_sizes, int n_in,
                              void* d_out, int out_size, void* d_ws, size_t ws_size,
                              hipStream_t stream) {
    const float* x    = (const float*)d_in[0];
    const float* wq   = (const float*)d_in[1];
    const float* bq   = (const float*)d_in[2];
    const float* wk   = (const float*)d_in[3];
    const float* bk   = (const float*)d_in[4];
    const float* wv   = (const float*)d_in[5];
    const float* bv   = (const float*)d_in[6];
    const float* wp   = (const float*)d_in[7];
    const float* bp   = (const float*)d_in[8];
    const float* w1   = (const float*)d_in[9];
    const float* b1   = (const float*)d_in[10];
    const float* w2   = (const float*)d_in[11];
    const float* b2   = (const float*)d_in[12];
    const float* ln1g = (const float*)d_in[13];
    const float* ln1b = (const float*)d_in[14];
    const float* lnfg = (const float*)d_in[15];
    const float* lnfb = (const float*)d_in[16];
    const float* ln2g = (const float*)d_in[17];
    const float* ln2b = (const float*)d_in[18];

    float* out2 = (float*)d_out;
    float* kv   = (float*)d_out + 4194304;   // Kc then Vc

    // workspace layout (bytes). Liveness:
    char* ws = (char*)d_ws;
    u16*   XB     = (u16*)  (ws + 0);          // 8 MB (dead after G1); CAT (dead after G3); Q5_0
    u16*   CAT    = XB;
    u16*   WQKVT  = (u16*)  (ws + 8388608);    // 6.3 MB (dead after G1)
    float* BQKV   = (float*)(ws + 14680064);   // 12 KB (dead after G1)
    u16*   WPT    = (u16*)  (ws + 14692352);   // 2 MB (dead after G3)
    u16*   W1T    = (u16*)  (ws + 16789504);   // 8 MB (dead after G4)
    u16*   W2T    = (u16*)  (ws + 25178112);   // 8 MB (live through G5)
    float* KTVF   = (float*)(ws + 33566720);   // 512 KB
    u16*   KTVT   = (u16*)  (ws + 34091008);   // 256 KB
    u16*   QKVB   = (u16*)  (ws + 34353152);   // 24 MB (dead after attn/kv_expand); OUT1B
    u16*   OUT1B  = QKVB;
    u16*   Q3_0   = (u16*)  (ws + 59518976);   // 8 MB (dead after ln1)
    u16*   Q3_1   = (u16*)  (ws + 67907584);   // 8 MB (dead after ln1)
    float* OUT1F  = (float*)(ws + 76296192);   // 16 MB (live to lnf)
    u16*   H1     = (u16*)  (ws + 93073408);   // 32 MB (live through G5)
    u16*   Q5_0   = (u16*)  (ws + 0);          // 8 MB (over XB/CAT, dead after G3)
    u16*   Q5_1   = (u16*)  (ws + 34353152);   // 8 MB (over OUT1B, dead after G4)
    (void)ws_size; (void)in_sizes; (void)n_in; (void)out_size;

    hipMemsetAsync(KTVF, 0, 32 * 4096 * 4, stream);
    cast_x_kernel<<<4096, 256, 0, stream>>>(x, XB);
    tr_wqkv<<<dim3(32, 2, 48), 256, 0, stream>>>(wq, wk, wv, WQKVT);
    prep_bias<<<12, 256, 0, stream>>>(bq, bk, bv, BQKV);
    transpose_cast<<<dim3(32, 32), 256, 0, stream>>>(wp, WPT, 1024, 1024);
    transpose_cast<<<dim3(128, 32), 256, 0, stream>>>(w1, W1T, 1024, 4096);
    transpose_cast<<<dim3(32, 128), 256, 0, stream>>>(w2, W2T, 4096, 1024);

    // G1: QKV = X @ Wqkv + b  (128x384 tile, grid 256, bf16 out only)
    gemmT<1, 2, 4, 4, 6, 2><<<256, 512, 0, stream>>>(
        XB, WQKVT, BQKV, QKVB, nullptr, nullptr,
        4096, 3072, 1024, 1024, 1024, 3072, 0);
    kv_expand<<<4096, 256, 0, stream>>>(QKVB, kv);
    ktv_partial<<<dim3(8, 32), 256, 0, stream>>>(QKVB, KTVF);
    cast_ktv<<<512, 256, 0, stream>>>(KTVF, KTVT);
    attn_gemm<<<dim3(32, 32), 256, 0, stream>>>(QKVB, KTVT, CAT);

    // G3: out = cat @ wp (128x128 tile, split-K x2, 512 blocks)
    gemmT<4, 2, 2, 4, 4, 1><<<512, 256, 0, stream>>>(
        CAT, WPT, nullptr, nullptr, Q3_0, Q3_1,
        4096, 1024, 1024, 1024, 1024, 1024, 512);
    ln1_kernel<<<4096, 256, 0, stream>>>(x, Q3_0, Q3_1, bp, ln1g, ln1b, OUT1F, OUT1B);

    // G4: h1 = relu(out1 @ w1 + b1) (256x256 tile, grid 256)
    gemmT<2, 2, 4, 8, 4, 2><<<256, 512, 0, stream>>>(
        OUT1B, W1T, b1, H1, nullptr, nullptr,
        4096, 4096, 1024, 1024, 1024, 4096, 0);
    // G5: ff = h1 @ w2 (128x128 tile, split-K x2 over K=4096, 512 blocks)
    gemmT<4, 2, 2, 4, 4, 1><<<512, 256, 0, stream>>>(
        H1, W2T, nullptr, nullptr, Q5_0, Q5_1,
        4096, 1024, 4096, 4096, 4096, 1024, 2048);
    lnf_kernel<<<4096, 256, 0, stream>>>(OUT1F, Q5_0, Q5_1, b2,
                                         lnfg, lnfb, ln2g, ln2b, out2);
}

// Round 7
// 209.568 us; speedup vs baseline: 1.4749x; 1.0523x over previous
//
#include <hip/hip_runtime.h>

typedef unsigned short u16;
typedef __attribute__((ext_vector_type(4))) float f32x4;
typedef __attribute__((ext_vector_type(8))) __bf16 bf16x8;
typedef __attribute__((ext_vector_type(8))) unsigned short u16x8;
typedef __attribute__((ext_vector_type(4))) unsigned short u16x4;

// ---------- scalar bf16 helpers ----------
__device__ __forceinline__ u16 f2b(float f) {
    unsigned int u = __builtin_bit_cast(unsigned int, f);
    u = (u + 0x7FFFu + ((u >> 16) & 1u)) >> 16;
    return (u16)u;
}
__device__ __forceinline__ float b2f(u16 h) {
    unsigned int u = ((unsigned int)h) << 16;
    return __builtin_bit_cast(float, u);
}

// async global->LDS, 16B per lane; LDS dest is wave-uniform base (+lane*16 by HW)
__device__ __forceinline__ void gload_lds16(const u16* g, u16* l) {
    __builtin_amdgcn_global_load_lds(
        (const __attribute__((address_space(1))) void*)g,
        (__attribute__((address_space(3))) void*)l,
        16, 0, 0);
}

__device__ __forceinline__ bf16x8 lds_frag(const u16* p) {
    u16x8 t = *(const u16x8*)p;
    return __builtin_bit_cast(bf16x8, t);
}

#define FENCE asm volatile("" ::: "memory")
#define BARRIER do { FENCE; __builtin_amdgcn_s_barrier(); FENCE; \
                     __builtin_amdgcn_sched_barrier(0); } while (0)
#define SCHED0 __builtin_amdgcn_sched_barrier(0)
#define LGKM0 do { asm volatile("s_waitcnt lgkmcnt(0)" ::: "memory"); \
                   __builtin_amdgcn_sched_barrier(0); } while (0)
#define WAIT_VM8 do { asm volatile("s_waitcnt vmcnt(8)" ::: "memory"); \
                      __builtin_amdgcn_sched_barrier(0); } while (0)
#define WAIT_VM0 do { asm volatile("s_waitcnt vmcnt(0)" ::: "memory"); \
                      __builtin_amdgcn_sched_barrier(0); } while (0)

// ---------------- prep kernels ----------------
__global__ __launch_bounds__(256) void cast_x_kernel(const float* __restrict__ in,
                                                     u16* __restrict__ out) {
    int i = (blockIdx.x * 256 + threadIdx.x) * 4;
    float4 v = *(const float4*)&in[i];
    u16x4 o = { f2b(v.x), f2b(v.y), f2b(v.z), f2b(v.w) };
    *(u16x4*)&out[i] = o;
}

// WT[(sel*1024 + h*64 + e)][d] = w_sel[h][d][e]  — LDS-tiled transpose
__global__ __launch_bounds__(256) void tr_wqkv(const float* __restrict__ wq,
                                               const float* __restrict__ wk,
                                               const float* __restrict__ wv,
                                               u16* __restrict__ WT) {
    __shared__ float tile[32][33];
    int z = blockIdx.z;                    // 0..47 = sel*16 + h
    int sel = z >> 4, h = z & 15;
    const float* w = (sel == 0) ? wq : (sel == 1) ? wk : wv;
    w += (long)h * 65536;                  // [1024][64]
    int tx = threadIdx.x & 31, ty = threadIdx.x >> 5;
    int d0 = blockIdx.x * 32, e0 = blockIdx.y * 32;
#pragma unroll
    for (int i = 0; i < 32; i += 8)
        tile[ty + i][tx] = w[(long)(d0 + ty + i) * 64 + e0 + tx];
    __syncthreads();
#pragma unroll
    for (int i = 0; i < 32; i += 8)
        WT[((long)(sel * 1024 + h * 64 + e0 + ty + i)) * 1024 + d0 + tx] = f2b(tile[tx][ty + i]);
}

__global__ __launch_bounds__(256) void prep_bias(const float* __restrict__ bq,
                                                 const float* __restrict__ bk,
                                                 const float* __restrict__ bv,
                                                 float* __restrict__ BI) {
    int i = blockIdx.x * 256 + threadIdx.x;   // < 3072
    const float* b = (i < 1024) ? bq : (i < 2048) ? bk : bv;
    BI[i] = b[((i & 1023) >> 6) * 64 + (i & 63)];
}

// out[c][r] = (bf16) in[r][c]   (in: [R][C] f32)
__global__ __launch_bounds__(256) void transpose_cast(const float* __restrict__ in,
                                                      u16* __restrict__ out, int R, int C) {
    __shared__ float tile[32][33];
    int tx = threadIdx.x & 31, ty = threadIdx.x >> 5;   // 32 x 8
    int r0 = blockIdx.y * 32, c0 = blockIdx.x * 32;
#pragma unroll
    for (int i = 0; i < 32; i += 8)
        tile[ty + i][tx] = in[(long)(r0 + ty + i) * C + c0 + tx];
    __syncthreads();
#pragma unroll
    for (int i = 0; i < 32; i += 8)
        out[(long)(c0 + ty + i) * R + r0 + tx] = f2b(tile[tx][ty + i]);
}

// Kc/Vc f32 expand from QKVB cols 1024..3071 (values bf16-exact)
__global__ __launch_bounds__(256) void kv_expand(const u16* __restrict__ QKVB,
                                                 float* __restrict__ kv) {
    int idx = blockIdx.x * 256 + threadIdx.x;  // 4096*2048/8 = 1,048,576
    int row = idx >> 8;
    int co = (idx & 255) * 8;                  // col in [0,2048), 8-aligned
    u16x8 v = *(const u16x8*)&QKVB[(long)row * 3072 + 1024 + co];
    float4 f0 = { b2f(v[0]), b2f(v[1]), b2f(v[2]), b2f(v[3]) };
    float4 f1 = { b2f(v[4]), b2f(v[5]), b2f(v[6]), b2f(v[7]) };
    long base = (long)(co >> 10) * 4194304 + (long)row * 1024 + (co & 1023);
    *(float4*)&kv[base] = f0;
    *(float4*)&kv[base + 4] = f1;
}

// ---------------- templated tiled GEMM, sub-phase pipelined (LDS || MFMA) -----
// C[M,N] = A[M,K] @ BT[N,K]^T. Tile BM=WM*MF*16, BN=WN*NF*16, BK=64, T=WM*WN*64.
// MODE 1: +bias, bf16 out (G1). MODE 2: +bias, relu (G4). MODE 4: 2-way split-K
// bf16 partials to Q0/Q1 (G3,G5).
// Pipeline: 4 sub-phases per K-tile, sub-phase s issues ds_reads for s+1 into the
// alternate register frag buffer, then MFMAs current frags. Compiler inserts
// counted lgkmcnt (m97 behavior) -> LDS reads overlap MFMA. Barriers: B1 (next
// slot visible) + B2 (slot safe to restage) per tile. Counted vmcnt only.
// LDS byte-swizzle col^=(row&7)<<4 via inverse-swizzled global src (rule #21).
// Epilogue: acc -> swizzled LDS repack -> coalesced u16x8 stores.
template <int MODE, int WM, int WN, int MF, int NF, bool COLOUT>
__global__ __launch_bounds__(WM * WN * 64, 2) void gemmT(
    const u16* __restrict__ A, const u16* __restrict__ BT, const float* __restrict__ bias,
    u16* __restrict__ Cb, u16* __restrict__ Q0, u16* __restrict__ Q1,
    int M, int N, int K, int lda, int ldb, int ldc, int kchunk) {
    constexpr int T   = WM * WN * 64;
    constexpr int BM  = WM * MF * 16;
    constexpr int BN  = WN * NF * 16;
    constexpr int RPI = T / 8;            // rows per gload instr
    constexpr int LA  = BM / RPI;         // gload instrs per A K-tile
    constexpr int LB  = BN / RPI;
    constexpr int EPI = T * 8;            // LDS elems per gload instr
    constexpr int MFH = MF / 2;
    constexpr int ASZ = BM * 64, BSZ = BN * 64;
    __shared__ __align__(16) u16 SMEM[2 * ASZ + 2 * BSZ];
    u16* As0 = SMEM;
    u16* As1 = SMEM + ASZ;
    u16* Bs0 = SMEM + 2 * ASZ;
    u16* Bs1 = SMEM + 2 * ASZ + BSZ;
    const int tid = threadIdx.x;
    const int lane = tid & 63;
    const int wid = tid >> 6;
    const int wr = wid / WN, wc = wid % WN;
    const int ntile = N / BN;
    const int mtile = M / BM;
    int bid = blockIdx.x;
    int kb = 0, ksz = K;
    u16* Pout = Q0;
    if (MODE == 4) {
        int tiles = mtile * ntile;
        int sk = bid / tiles; bid -= sk * tiles;
        kb = sk * kchunk;
        int rem = K - kb; ksz = rem < kchunk ? rem : kchunk;
        Pout = sk ? Q1 : Q0;
    }
    // XCD-chunked bijective swizzle (tile count multiple of 8)
    {
        int q = (mtile * ntile) >> 3;
        bid = (bid & 7) * q + (bid >> 3);
    }
    int bi, bj;
    if (COLOUT) { bj = bid / mtile; bi = bid % mtile; }   // XCD owns B col-panels (G1)
    else        { bi = bid / ntile; bj = bid % ntile; }   // XCD owns A row-panels
    const int brow = bi * BM, bcol = bj * BN;
    const int nt = ksz >> 6;              // BK=64 tiles

    // ---- staging addressing (inverse-swizzled global source, linear LDS dest)
    const int srow = tid >> 3;
    const int scol = ((tid & 7) ^ (srow & 7)) << 3;
    const u16* ag = A + (long)(brow + srow) * lda + kb + scol;
    const u16* bg = BT + (long)(bcol + srow) * ldb + kb + scol;
    const long aI = (long)RPI * lda, bI = (long)RPI * ldb;
    const int sdst = tid << 3;

    auto STAGE = [&](u16* lA, u16* lB, int t) {
#pragma unroll
        for (int j = 0; j < LA; ++j)
            gload_lds16(ag + ((long)t << 6) + j * aI, &lA[j * EPI + sdst]);
#pragma unroll
        for (int j = 0; j < LB; ++j)
            gload_lds16(bg + ((long)t << 6) + j * bI, &lB[j * EPI + sdst]);
    };

    f32x4 acc[MF][NF] = {};
    bf16x8 af0[MFH], af1[MFH], bf0[NF], bf1[NF];

    // ---- fragment read addressing (swizzled)
    const int ln15 = lane & 15;
    const int eoff = (((lane >> 4) << 3) ^ ((lane & 7) << 3));
    const int arow0 = wr * (MF * 16) + ln15;
    const int brow0 = wc * (NF * 16) + ln15;

#define RD_A(dst, S, kh, mh)                                                   \
    _Pragma("unroll") for (int m4 = 0; m4 < MFH; ++m4)                         \
        dst[m4] = lds_frag(&(S)[((arow0 + (((mh) * MFH + m4) << 4)) << 6) +    \
                                (eoff ^ ((kh) << 5))]);
#define RD_B(dst, S, kh)                                                       \
    _Pragma("unroll") for (int n = 0; n < NF; ++n)                             \
        dst[n] = lds_frag(&(S)[((brow0 + (n << 4)) << 6) + (eoff ^ ((kh) << 5))]);
#define MM(a, b, mh) do {                                                      \
    __builtin_amdgcn_s_setprio(1);                                             \
    _Pragma("unroll") for (int m4 = 0; m4 < MFH; ++m4)                         \
        _Pragma("unroll") for (int n = 0; n < NF; ++n)                         \
            acc[(mh) * MFH + m4][n] = __builtin_amdgcn_mfma_f32_16x16x32_bf16( \
                a[m4], b[n], acc[(mh) * MFH + m4][n], 0, 0, 0);                \
    __builtin_amdgcn_s_setprio(0);                                             \
} while (0)

    // ---- prologue: stage t0 + t1; retire t0; initial frags
    STAGE(As0, Bs0, 0);
    if (nt > 1) { STAGE(As1, Bs1, 1); WAIT_VM8; } else { WAIT_VM0; }
    BARRIER;
    RD_B(bf0, Bs0, 0);
    RD_A(af0, As0, 0, 0);

    u16 *Ac = As0, *Bc = Bs0, *Ao = As1, *Bo = Bs1;
    for (int t = 0; t < nt; ++t) {
        const bool hasN = (t + 1 < nt);
        const bool hasNN = (t + 2 < nt);
        // s0: compute (kh0, mh0); prefetch (kh0, mh1)
        RD_A(af1, Ac, 0, 1);
        MM(af0, bf0, 0);
        SCHED0;
        // s1: compute (kh0, mh1); prefetch kh1 B + (kh1, mh0)
        RD_B(bf1, Bc, 1);
        RD_A(af0, Ac, 1, 0);
        MM(af1, bf0, 1);
        SCHED0;
        // s2: compute (kh1, mh0); prefetch (kh1, mh1)
        RD_A(af1, Ac, 1, 1);
        MM(af0, bf1, 0);
        WAIT_VM0;            // stage(t+1 -> other slot) retired
        BARRIER;             // B1: next tile visible
        // s3: compute (kh1, mh1); prefetch next tile (kh0) from other slot
        if (hasN) { RD_B(bf0, Bo, 0); RD_A(af0, Ao, 0, 0); }
        MM(af1, bf1, 1);
        BARRIER;             // B2: all waves done reading current slot
        if (hasNN) STAGE(Ac, Bc, t + 2);
        SCHED0;
        u16* tp;
        tp = Ac; Ac = Ao; Ao = tp;
        tp = Bc; Bc = Bo; Bo = tp;
    }

    // ---- epilogue: swizzled LDS repack -> coalesced stores
    const int crow0 = wr * (MF * 16), ccol0 = wc * (NF * 16);
#pragma unroll
    for (int m = 0; m < MF; ++m) {
        int rbase = crow0 + (m << 4) + ((lane >> 4) << 2);
#pragma unroll
        for (int n = 0; n < NF; ++n) {
            int col = ccol0 + (n << 4) + ln15;
            float bv = (MODE == 4) ? 0.f : bias[bcol + col];
#pragma unroll
            for (int r = 0; r < 4; ++r) {
                float v = acc[m][n][r] + bv;
                if (MODE == 2) v = v > 0.f ? v : 0.f;
                int row = rbase + r;
                SMEM[row * BN + (col ^ ((row & 7) << 3))] = f2b(v);
            }
        }
    }
    LGKM0;
    BARRIER;
    u16* outp = (MODE == 4) ? Pout : Cb;
    constexpr int CHT = BM * BN / 8 / T;
#pragma unroll
    for (int k = 0; k < CHT; ++k) {
        int c = tid + k * T;
        int row = c / (BN / 8), co = (c % (BN / 8)) * 8;
        u16x8 vv = *(const u16x8*)&SMEM[row * BN + (co ^ ((row & 7) << 3))];
        *(u16x8*)&outp[(long)(brow + row) * ldc + bcol + co] = vv;
    }
#undef RD_A
#undef RD_B
#undef MM
}

// ---------------- K^T V partial sums (t-chunked, f32 atomics) ----------------
__global__ __launch_bounds__(256) void ktv_partial(const u16* __restrict__ QKVB,
                                                   float* __restrict__ KTVF) {
    __shared__ __align__(16) u16 Ks[64 * 64];
    __shared__ __align__(16) u16 Vs[64 * 64];
    int tid = threadIdx.x;
    int tc = blockIdx.x, bh = blockIdx.y;
    int b = bh >> 4, h = bh & 15;
    int j = tid & 63, i0 = (tid >> 6) * 16;
    float acc[16] = {};
    for (int st = 0; st < 4; ++st) {
        int t0 = tc * 256 + st * 64;
        __syncthreads();
#pragma unroll
        for (int i = 0; i < 2; ++i) {
            int c = i * 256 + tid;
            long base = (long)(b * 2048 + t0 + (c >> 3)) * 3072 + h * 64 + (c & 7) * 8;
            *(u16x8*)&Ks[c * 8] = *(const u16x8*)&QKVB[base + 1024];
            *(u16x8*)&Vs[c * 8] = *(const u16x8*)&QKVB[base + 2048];
        }
        __syncthreads();
        for (int tt = 0; tt < 64; ++tt) {
            float vj = b2f(Vs[tt * 64 + j]);
            u16x8 k0 = *(const u16x8*)&Ks[tt * 64 + i0];
            u16x8 k1 = *(const u16x8*)&Ks[tt * 64 + i0 + 8];
#pragma unroll
            for (int r = 0; r < 8; ++r) acc[r] += b2f(k0[r]) * vj;
#pragma unroll
            for (int r = 0; r < 8; ++r) acc[r + 8] += b2f(k1[r]) * vj;
        }
    }
#pragma unroll
    for (int r = 0; r < 16; ++r)
        atomicAdd(&KTVF[bh * 4096 + (i0 + r) * 64 + j], acc[r]);
}

// KTVT[bh][n][k] = KTVF[bh][k][n] * 0.125 (fold 1/sqrt(64))
__global__ __launch_bounds__(256) void cast_ktv(const float* __restrict__ KTVF,
                                                u16* __restrict__ KTVT) {
    int idx = blockIdx.x * 256 + threadIdx.x;   // < 32*4096
    int bh = idx >> 12, r = idx & 4095;
    int n = r >> 6, k = r & 63;
    KTVT[idx] = f2b(KTVF[bh * 4096 + k * 64 + n] * 0.125f);
}

// ---------------- batched attn GEMM: cat[t, h*64+e'] = Q[t,:] @ KTVT[e',:] -------
__global__ __launch_bounds__(256) void attn_gemm(const u16* __restrict__ QKVB,
                                                 const u16* __restrict__ KTVT,
                                                 u16* __restrict__ cat) {
    __shared__ __align__(16) u16 Qs[64 * 64];
    __shared__ __align__(16) u16 Bs[64 * 64];
    int tid = threadIdx.x, wid = tid >> 6, lane = tid & 63;
    int rt = blockIdx.x, bh = blockIdx.y;
    int b = bh >> 4, h = bh & 15;
    long qbase = (long)(b * 2048 + rt * 64) * 3072 + h * 64;
#pragma unroll
    for (int i = 0; i < 2; ++i) {
        int c = i * 256 + tid;
        gload_lds16(QKVB + qbase + (c >> 3) * 3072 + (c & 7) * 8, &Qs[(i * 256 + wid * 64) * 8]);
        gload_lds16(KTVT + bh * 4096 + c * 8, &Bs[(i * 256 + wid * 64) * 8]);
    }
    __syncthreads();
    f32x4 acc[4] = {};
#pragma unroll
    for (int kk = 0; kk < 2; ++kk) {
        bf16x8 a = lds_frag(&Qs[(wid * 16 + (lane & 15)) * 64 + kk * 32 + (lane >> 4) * 8]);
#pragma unroll
        for (int n = 0; n < 4; ++n) {
            bf16x8 bb = lds_frag(&Bs[(n * 16 + (lane & 15)) * 64 + kk * 32 + (lane >> 4) * 8]);
            acc[n] = __builtin_amdgcn_mfma_f32_16x16x32_bf16(a, bb, acc[n], 0, 0, 0);
        }
    }
#pragma unroll
    for (int n = 0; n < 4; ++n)
#pragma unroll
        for (int r = 0; r < 4; ++r) {
            int row = rt * 64 + wid * 16 + (lane >> 4) * 4 + r;
            int col = h * 64 + n * 16 + (lane & 15);
            cat[(long)(b * 2048 + row) * 1024 + col] = f2b(acc[n][r]);
        }
}

// ---------------- layernorm kernels ----------------
__device__ __forceinline__ void block_reduce2(float& a, float& b) {
    __syncthreads();
#pragma unroll
    for (int off = 32; off; off >>= 1) {
        a += __shfl_down(a, off);
        b += __shfl_down(b, off);
    }
    __shared__ float sa[4], sb[4];
    int wid = threadIdx.x >> 6, lane = threadIdx.x & 63;
    if (lane == 0) { sa[wid] = a; sb[wid] = b; }
    __syncthreads();
    a = sa[0] + sa[1] + sa[2] + sa[3];
    b = sb[0] + sb[1] + sb[2] + sb[3];
}

// out1 = LN(x + (q0+q1 + bp)) ; write f32 + bf16  (q* = bf16 partials)
__global__ __launch_bounds__(256) void ln1_kernel(
    const float* __restrict__ x,
    const u16* __restrict__ q0, const u16* __restrict__ q1,
    const float* __restrict__ bp,
    const float* __restrict__ g, const float* __restrict__ bt,
    float* __restrict__ out1f, u16* __restrict__ out1b) {
    int row = blockIdx.x, tid = threadIdx.x;
    long base = (long)row * 1024 + tid * 4;
    float4 xv = *(const float4*)&x[base];
    u16x4 a0 = *(const u16x4*)&q0[base];
    u16x4 a1 = *(const u16x4*)&q1[base];
    float4 bb = *(const float4*)&bp[tid * 4];
    float xa[4] = { xv.x, xv.y, xv.z, xv.w };
    float bba[4] = { bb.x, bb.y, bb.z, bb.w };
    float s[4];
#pragma unroll
    for (int r = 0; r < 4; ++r)
        s[r] = xa[r] + b2f(a0[r]) + b2f(a1[r]) + bba[r];
    float sum = s[0] + s[1] + s[2] + s[3];
    float sq = s[0] * s[0] + s[1] * s[1] + s[2] * s[2] + s[3] * s[3];
    block_reduce2(sum, sq);
    float mu = sum * (1.f / 1024.f);
    float var = sq * (1.f / 1024.f) - mu * mu;
    float rs = rsqrtf(var + 1e-5f);
    float o0 = (s[0] - mu) * rs * g[tid * 4 + 0] + bt[tid * 4 + 0];
    float o1 = (s[1] - mu) * rs * g[tid * 4 + 1] + bt[tid * 4 + 1];
    float o2 = (s[2] - mu) * rs * g[tid * 4 + 2] + bt[tid * 4 + 2];
    float o3 = (s[3] - mu) * rs * g[tid * 4 + 3] + bt[tid * 4 + 3];
    float4 of; of.x = o0; of.y = o1; of.z = o2; of.w = o3;
    u16x4 ob = (u16x4){ f2b(o0), f2b(o1), f2b(o2), f2b(o3) };
    *(float4*)&out1f[base] = of;
    *(u16x4*)&out1b[base] = ob;
}

// ff = (q0+q1)+b2 (bf16 partials); ffo = LN(out1+ff); out2 = LN(out1+ffo)
__global__ __launch_bounds__(256) void lnf_kernel(
    const float* __restrict__ out1f,
    const u16* __restrict__ q0, const u16* __restrict__ q1,
    const float* __restrict__ b2,
    const float* __restrict__ lnfg, const float* __restrict__ lnfb,
    const float* __restrict__ ln2g, const float* __restrict__ ln2b,
    float* __restrict__ out2) {
    int row = blockIdx.x, tid = threadIdx.x;
    long base = (long)row * 1024 + tid * 4;
    float4 o1 = *(const float4*)&out1f[base];
    u16x4 a0 = *(const u16x4*)&q0[base];
    u16x4 a1 = *(const u16x4*)&q1[base];
    float4 bb = *(const float4*)&b2[tid * 4];
    float o1a[4] = { o1.x, o1.y, o1.z, o1.w };
    float bba[4] = { bb.x, bb.y, bb.z, bb.w };
    float s1[4];
#pragma unroll
    for (int r = 0; r < 4; ++r)
        s1[r] = o1a[r] + b2f(a0[r]) + b2f(a1[r]) + bba[r];
    float sum = s1[0] + s1[1] + s1[2] + s1[3];
    float sq = s1[0] * s1[0] + s1[1] * s1[1] + s1[2] * s1[2] + s1[3] * s1[3];
    block_reduce2(sum, sq);
    float mu = sum * (1.f / 1024.f);
    float rs = rsqrtf(sq * (1.f / 1024.f) - mu * mu + 1e-5f);
    float s2[4];
#pragma unroll
    for (int r = 0; r < 4; ++r) {
        float ffo = (s1[r] - mu) * rs * lnfg[tid * 4 + r] + lnfb[tid * 4 + r];
        s2[r] = o1a[r] + ffo;
    }
    float sum2 = s2[0] + s2[1] + s2[2] + s2[3];
    float sq2 = s2[0] * s2[0] + s2[1] * s2[1] + s2[2] * s2[2] + s2[3] * s2[3];
    block_reduce2(sum2, sq2);
    float mu2 = sum2 * (1.f / 1024.f);
    float rs2 = rsqrtf(sq2 * (1.f / 1024.f) - mu2 * mu2 + 1e-5f);
    float4 o;
    o.x = (s2[0] - mu2) * rs2 * ln2g[tid * 4 + 0] + ln2b[tid * 4 + 0];
    o.y = (s2[1] - mu2) * rs2 * ln2g[tid * 4 + 1] + ln2b[tid * 4 + 1];
    o.z = (s2[2] - mu2) * rs2 * ln2g[tid * 4 + 2] + ln2b[tid * 4 + 2];
    o.w = (s2[3] - mu2) * rs2 * ln2g[tid * 4 + 3] + ln2b[tid * 4 + 3];
    *(float4*)&out2[base] = o;
}

// ---------------- launcher ----------------
extern "C" void kernel_launch(void* const* d_in, const int* in_sizes, int n_in,
                              void* d_out, int out_size, void* d_ws, size_t ws_size,
                              hipStream_t stream) {
    const float* x    = (const float*)d_in[0];
    const float* wq   = (const float*)d_in[1];
    const float* bq   = (const float*)d_in[2];
    const float* wk   = (const float*)d_in[3];
    const float* bk   = (const float*)d_in[4];
    const float* wv   = (const float*)d_in[5];
    const float* bv   = (const float*)d_in[6];
    const float* wp   = (const float*)d_in[7];
    const float* bp   = (const float*)d_in[8];
    const float* w1   = (const float*)d_in[9];
    const float* b1   = (const float*)d_in[10];
    const float* w2   = (const float*)d_in[11];
    const float* b2   = (const float*)d_in[12];
    const float* ln1g = (const float*)d_in[13];
    const float* ln1b = (const float*)d_in[14];
    const float* lnfg = (const float*)d_in[15];
    const float* lnfb = (const float*)d_in[16];
    const float* ln2g = (const float*)d_in[17];
    const float* ln2b = (const float*)d_in[18];

    float* out2 = (float*)d_out;
    float* kv   = (float*)d_out + 4194304;   // Kc then Vc

    // workspace layout (bytes). Liveness:
    char* ws = (char*)d_ws;
    u16*   XB     = (u16*)  (ws + 0);          // 8 MB (dead after G1); CAT (dead after G3); Q5_0
    u16*   CAT    = XB;
    u16*   WQKVT  = (u16*)  (ws + 8388608);    // 6.3 MB (dead after G1)
    float* BQKV   = (float*)(ws + 14680064);   // 12 KB (dead after G1)
    u16*   WPT    = (u16*)  (ws + 14692352);   // 2 MB (dead after G3)
    u16*   W1T    = (u16*)  (ws + 16789504);   // 8 MB (dead after G4)
    u16*   W2T    = (u16*)  (ws + 25178112);   // 8 MB (live through G5)
    float* KTVF   = (float*)(ws + 33566720);   // 512 KB
    u16*   KTVT   = (u16*)  (ws + 34091008);   // 256 KB
    u16*   QKVB   = (u16*)  (ws + 34353152);   // 24 MB (dead after attn/kv_expand); OUT1B
    u16*   OUT1B  = QKVB;
    u16*   Q3_0   = (u16*)  (ws + 59518976);   // 8 MB (dead after ln1)
    u16*   Q3_1   = (u16*)  (ws + 67907584);   // 8 MB (dead after ln1)
    float* OUT1F  = (float*)(ws + 76296192);   // 16 MB (live to lnf)
    u16*   H1     = (u16*)  (ws + 93073408);   // 32 MB (live through G5)
    u16*   Q5_0   = (u16*)  (ws + 0);          // 8 MB (over XB/CAT, dead after G3)
    u16*   Q5_1   = (u16*)  (ws + 34353152);   // 8 MB (over OUT1B, dead after G4)
    (void)ws_size; (void)in_sizes; (void)n_in; (void)out_size;

    hipMemsetAsync(KTVF, 0, 32 * 4096 * 4, stream);
    cast_x_kernel<<<4096, 256, 0, stream>>>(x, XB);
    tr_wqkv<<<dim3(32, 2, 48), 256, 0, stream>>>(wq, wk, wv, WQKVT);
    prep_bias<<<12, 256, 0, stream>>>(bq, bk, bv, BQKV);
    transpose_cast<<<dim3(32, 32), 256, 0, stream>>>(wp, WPT, 1024, 1024);
    transpose_cast<<<dim3(128, 32), 256, 0, stream>>>(w1, W1T, 1024, 4096);
    transpose_cast<<<dim3(32, 128), 256, 0, stream>>>(w2, W2T, 4096, 1024);

    // G1: QKV = X @ Wqkv + b  (128x384 tile, grid 256, col-outer XCD swizzle)
    gemmT<1, 2, 4, 4, 6, true><<<256, 512, 0, stream>>>(
        XB, WQKVT, BQKV, QKVB, nullptr, nullptr,
        4096, 3072, 1024, 1024, 1024, 3072, 0);
    kv_expand<<<4096, 256, 0, stream>>>(QKVB, kv);
    ktv_partial<<<dim3(8, 32), 256, 0, stream>>>(QKVB, KTVF);
    cast_ktv<<<512, 256, 0, stream>>>(KTVF, KTVT);
    attn_gemm<<<dim3(32, 32), 256, 0, stream>>>(QKVB, KTVT, CAT);

    // G3: out = cat @ wp (128x128 tile, split-K x2, 512 blocks, row-outer)
    gemmT<4, 2, 2, 4, 4, false><<<512, 256, 0, stream>>>(
        CAT, WPT, nullptr, nullptr, Q3_0, Q3_1,
        4096, 1024, 1024, 1024, 1024, 1024, 512);
    ln1_kernel<<<4096, 256, 0, stream>>>(x, Q3_0, Q3_1, bp, ln1g, ln1b, OUT1F, OUT1B);

    // G4: h1 = relu(out1 @ w1 + b1) (256x256 tile, grid 256, row-outer)
    gemmT<2, 2, 4, 8, 4, false><<<256, 512, 0, stream>>>(
        OUT1B, W1T, b1, H1, nullptr, nullptr,
        4096, 4096, 1024, 1024, 1024, 4096, 0);
    // G5: ff = h1 @ w2 (128x128 tile, split-K x2 over K=4096, 512 blocks, row-outer)
    gemmT<4, 2, 2, 4, 4, false><<<512, 256, 0, stream>>>(
        H1, W2T, nullptr, nullptr, Q5_0, Q5_1,
        4096, 1024, 4096, 4096, 4096, 1024, 2048);
    lnf_kernel<<<4096, 256, 0, stream>>>(OUT1F, Q5_0, Q5_1, b2,
                                         lnfg, lnfb, ln2g, ln2b, out2);
}